// Round 17
// baseline (453.315 us; speedup 1.0000x reference)
//
#include <hip/hip_runtime.h>
#include <math.h>

#define TILE_E 16
#define NINS 11
#define IND 288
#define SHD 9
#define W2N 11264
#define YROW 164    // ybuf row stride (f32): (164e)%32=4e -> b128 reads 2-way (free)
#define SHWP 28     // shw row pad

typedef _Float16 half8 __attribute__((ext_vector_type(8)));
typedef float f32x4 __attribute__((ext_vector_type(4)));

constexpr int kL1[NINS] = {0,0,0,1,1,1,1,2,2,2,2};
constexpr int kL2[NINS] = {0,1,2,0,1,1,2,0,1,2,2};
constexpr int kL3[NINS] = {0,1,2,1,0,2,1,2,1,0,2};
constexpr int kW3OFF[NINS] = {0,1,10,35,44,53,98,143,168,213,238};

// ---------------- Wigner 3j (exact port of reference) ----------------
__device__ double dfac(int n){ double r=1.0; for(int i=2;i<=n;++i) r*=(double)i; return r; }

__device__ void qmat_dev(int l,double* qr,double* qi){
  int d=2*l+1;
  for(int i=0;i<d*d;++i){qr[i]=0.0;qi[i]=0.0;}
  const double s=0.70710678118654752440;
  for(int m=-l;m<0;++m){
    qr[(l+m)*d+(l-m)]=s;
    qi[(l+m)*d+(l+m)]=-s;
  }
  qr[l*d+l]=1.0;
  for(int m=1;m<=l;++m){
    double sg=(m&1)?-1.0:1.0;
    qr[(l+m)*d+(l+m)]=sg*s;
    qi[(l+m)*d+(l-m)]=sg*s;
  }
  if(l==1){ for(int i=0;i<d*d;++i){ double a=qr[i],b=qi[i]; qr[i]=b; qi[i]=-a; } }
  else if(l==2){ for(int i=0;i<d*d;++i){ qr[i]=-qr[i]; qi[i]=-qi[i]; } }
}

__device__ void w3j_body(int ins, int t, float* w3j){
  const int l1=kL1[ins],l2=kL2[ins],l3=kL3[ins];
  const int d1=2*l1+1,d2=2*l2+1,d3=2*l3+1;
  const int n=d1*d2*d3;

  __shared__ double C[125];
  __shared__ double R[125];
  __shared__ double q1r[25],q1i[25],q2r[25],q2i[25],q3r[25],q3i[25];
  __shared__ double inv;

  for(int i=t;i<125;i+=256) C[i]=0.0;
  if(t==0){
    qmat_dev(l1,q1r,q1i); qmat_dev(l2,q2r,q2i); qmat_dev(l3,q3r,q3i);
  }
  __syncthreads();

  if(t<d1*d2){
    int m1=t/d2-l1, m2=t-(t/d2)*d2-l2;
    int m3=m1+m2;
    if(m3>=-l3 && m3<=l3){
      int vmin=-l1+l2+m3; if(-l1+m1>vmin)vmin=-l1+m1; if(0>vmin)vmin=0;
      int vmax=l2+l3+m1; if(l3-l1+l2<vmax)vmax=l3-l1+l2; if(l3+m3<vmax)vmax=l3+m3;
      double c=sqrt((double)(2*l3+1)*dfac(l3+l1-l2)*dfac(l3-l1+l2)*dfac(l1+l2-l3)
        *dfac(l3+m3)*dfac(l3-m3)
        /(dfac(l1+l2+l3+1)*dfac(l1-m1)*dfac(l1+m1)*dfac(l2-m2)*dfac(l2+m2)));
      double s=0.0;
      for(int v=vmin;v<=vmax;++v){
        double term=dfac(l2+l3+m1-v)*dfac(l1-m1+v)
          /(dfac(v)*dfac(l3-l1+l2-v)*dfac(l3+m3-v)*dfac(v+l1-l2-m3));
        s += (((v+l2+m2)&1)?-1.0:1.0)*term;
      }
      C[((m1+l1)*d2+(m2+l2))*d3+(m3+l3)]=c*s;
    }
  }
  __syncthreads();

  if(t<n){
    int j=t/(d2*d3);
    int rem=t-j*(d2*d3);
    int l=rem/d3, m=rem-l*d3;
    double sr=0.0;
    for(int a=0;a<d1;++a)for(int b=0;b<d2;++b)for(int nn=0;nn<d3;++nn){
      double cv=C[(a*d2+b)*d3+nn];
      if(cv==0.0) continue;
      double xr=q1r[a*d1+j],xi=q1i[a*d1+j];
      double yr=q2r[b*d2+l],yi=q2i[b*d2+l];
      double zr=q3r[nn*d3+m],zi=-q3i[nn*d3+m];
      double pr=xr*yr-xi*yi, pi=xr*yi+xi*yr;
      sr += (pr*zr-pi*zi)*cv;
    }
    R[t]=sr;
  }
  __syncthreads();
  if(t==0){
    double n2=0.0;
    for(int i=0;i<n;++i) n2+=R[i]*R[i];
    inv=1.0/sqrt(n2);
  }
  __syncthreads();
  if(t<n) w3j[kW3OFF[ins]+t]=(float)(R[t]*inv);
}

__device__ void pack_body(int pb, int t, const float* __restrict__ W2,
                          _Float16* __restrict__ w2h){
  int q = pb*256 + t;                        // 704*2*64 = 90112
  if(q >= 704*2*64) return;
  int l = q & 63;
  int s = (q>>6)&1;
  int g = q>>7;
  int ins=g>>6, rem=g&63, uc=rem>>4, tp=rem&15;
  int m = l&15;
  int col = ins*1024 + (uc*8 + (m&7))*32 + tp*2 + (m>>3);
  int c0  = s*32 + ((l>>4)<<3);
  half8 v;
  #pragma unroll
  for(int i=0;i<8;++i) v[i] = (_Float16)W2[(size_t)(c0+i)*W2N + col];
  *(half8*)&w2h[(size_t)q*8] = v;
}

__device__ void h_body(int hb, int t, const float* __restrict__ radial,
    const float* __restrict__ W1, _Float16* __restrict__ h16g, int E, float silu_cst){
  int idx = hb*256 + t;
  int e = idx>>6, c = idx&63;
  if(e>=E) return;
  const float* rr = radial + (size_t)e*64;
  float acc=0.f;
  #pragma unroll 8
  for(int r=0;r<64;++r) acc += rr[r]*W1[r*64+c];
  acc*=0.125f;
  float hv = silu_cst*acc/(1.f+expf(-acc));
  h16g[idx]=(_Float16)hv;
}

// CSR hist + scan + fill in one block (n <= 2048)
__device__ void csr_body(int t, const int* __restrict__ eidx,
    int* __restrict__ rowptr, int* __restrict__ elist, int E, int n){
  __shared__ int deg[2048];
  __shared__ int psum[256];
  for(int i=t;i<2048;i+=256) deg[i]=0;
  __syncthreads();
  for(int e=t;e<E;e+=256) atomicAdd(&deg[eidx[E+e]],1);
  __syncthreads();
  int base=t*8;
  int loc[8]; int s=0;
  #pragma unroll
  for(int i=0;i<8;++i){ loc[i]=(base+i<n)?deg[base+i]:0; s+=loc[i]; }
  psum[t]=s;
  __syncthreads();
  for(int off=1; off<256; off<<=1){
    int v=psum[t];
    int add=(t>=off)?psum[t-off]:0;
    __syncthreads();
    psum[t]=v+add;
    __syncthreads();
  }
  int excl=psum[t]-s;
  #pragma unroll
  for(int i=0;i<8;++i){
    if(base+i<n){ rowptr[base+i]=excl; deg[base+i]=excl; }  // deg becomes LDS cursor
    excl+=loc[i];
  }
  if(t==255) rowptr[n]=psum[255];
  __syncthreads();
  for(int e=t;e<E;e+=256){
    int d=eidx[E+e];
    int pos=atomicAdd(&deg[d],1);
    elist[pos]=e;
  }
}

// one launch: [0,11)=w3j, [11,363)=pack_w2, [363,363+hblocks)=h, optional last=csr(+fill)
__global__ __launch_bounds__(256) void prep_kernel(float* w3j,
    const float* __restrict__ W2, _Float16* __restrict__ w2h,
    const float* __restrict__ radial, const float* __restrict__ W1,
    _Float16* __restrict__ h16g, int E, float silu_cst,
    const int* __restrict__ eidx, int* __restrict__ rowptr, int* __restrict__ elist,
    int n_nodes, int hblocks){
  int b=blockIdx.x, t=threadIdx.x;
  if(b<NINS)                  w3j_body(b, t, w3j);
  else if(b<NINS+352)         pack_body(b-NINS, t, W2, w2h);
  else if(b<NINS+352+hblocks) h_body(b-NINS-352, t, radial, W1, h16g, E, silu_cst);
  else                        csr_body(t, eidx, rowptr, elist, E, n_nodes);
}

// ---------------- gather + fused self-connection ----------------
__global__ __launch_bounds__(256) void gather_kernel(const float* __restrict__ msgbuf,
    const int* __restrict__ rowptr, const int* __restrict__ elist,
    const float* __restrict__ x,
    const float* __restrict__ W0, const float* __restrict__ W1s, const float* __restrict__ W2s,
    float* __restrict__ out, int n_nodes)
{
  int n=blockIdx.x;
  if(n>=n_nodes) return;
  int s0=rowptr[n], s1=rowptr[n+1];
  const float inv=0.17677669529663689f;  // 1/sqrt(32)
  for(int o=threadIdx.x; o<IND; o+=blockDim.x){
    float acc=0.f;
    for(int j=s0;j<s1;++j)
      acc += msgbuf[(size_t)elist[j]*IND + o];
    const float* W; int w,k,d,xo;
    if(o<32){W=W0; w=o; k=0; d=1; xo=0;}
    else if(o<128){int r=o-32; W=W1s; d=3; w=r/3; k=r-w*3; xo=32;}
    else {int r=o-128; W=W2s; d=5; w=r/5; k=r-w*5; xo=128;}
    float ssc=0.f;
    const float* xr=x+(size_t)n*IND+xo+k;
    for(int u=0;u<32;++u) ssc += xr[u*d]*W[u*32+w];
    out[(size_t)n*IND+o]=acc + ssc*inv;
  }
}

// ---------------- self connection (fallback path only) ----------------
__global__ __launch_bounds__(256) void sc_kernel(const float* __restrict__ x,
  const float* __restrict__ W0, const float* __restrict__ W1s, const float* __restrict__ W2s,
  float* __restrict__ out, int n_nodes)
{
  int n=blockIdx.x;
  if(n>=n_nodes) return;
  const float inv=0.17677669529663689f;
  for(int o=threadIdx.x; o<IND; o+=blockDim.x){
    const float* W; int w,k,d,xo;
    if(o<32){W=W0; w=o; k=0; d=1; xo=0;}
    else if(o<128){int r=o-32; W=W1s; d=3; w=r/3; k=r-w*3; xo=32;}
    else {int r=o-128; W=W2s; d=5; w=r/5; k=r-w*5; xo=128;}
    float s=0.f;
    const float* xr=x+(size_t)n*IND+xo+k;
    for(int u=0;u<32;++u) s += xr[u*d]*W[u*32+w];
    out[(size_t)n*IND+o]=s*inv;
  }
}

// ---------------- tp building blocks ----------------
template<int INS>
__device__ __forceinline__ void b1_step(const float* __restrict__ w3j,
    const float* __restrict__ sh, float (*shw)[SHWP], int t, int e0, int E)
{
  constexpr int L1v=kL1[INS], L2v=kL2[INS];
  constexpr int D1=2*L1v+1, D2=2*L2v+1, D3=2*kL3[INS]+1;
  constexpr int SO=(L2v==0)?0:(L2v==1?1:4);
  const float* w3=w3j+kW3OFF[INS];
  constexpr int NN=TILE_E*D1*D3;
  for(int idx=t; idx<NN; idx+=256){
    int e=idx/(D1*D3), r=idx-e*(D1*D3);
    int i=r/D3, k=r-i*D3;
    int eg=e0+e;
    float s=0.f;
    if(eg<E){
      #pragma unroll
      for(int j=0;j<D2;++j) s += w3[(i*D2+j)*D3+k]*sh[(size_t)eg*SHD+SO+j];
    }
    shw[e][r]=s;
  }
}

template<int INS>
__device__ __forceinline__ void b2_step(const float* __restrict__ x,
    const int* __restrict__ eidx, const float (*shw)[SHWP], float (*yb)[YROW],
    int t, int e0, int E)
{
  constexpr int L1v=kL1[INS];
  constexpr int D1=2*L1v+1, D3=2*kL3[INS]+1;
  constexpr int XO=(L1v==0)?0:(L1v==1?32:128);
  constexpr int NN=TILE_E*32*D3;
  for(int idx=t; idx<NN; idx+=256){
    int e=idx/(32*D3), r=idx-e*(32*D3);
    int k=r>>5, u=r&31;
    int eg=e0+e;
    float s=0.f;
    if(eg<E){
      int srn=eidx[eg];
      const float* xr=x+(size_t)srn*IND+XO+u*D1;
      #pragma unroll
      for(int i=0;i<D1;++i) s += shw[e][i*D3+k]*xr[i];
    }
    yb[e][k*32+u]=s;
  }
}

// compute phase: depth-1 af register prefetch across uc (fully unrolled, static regs)
template<int INS, int ND3>
__device__ __forceinline__ void comp_step(const float (*yb)[YROW],
    const half8* __restrict__ w2p,
    half8 hb0, half8 hb1,
    int ln, int eA, int upb, int wv,
    float (&p0)[4*ND3])
{
  constexpr int D3=2*kL3[INS]+1;
  static_assert(D3==ND3, "group/ins D3 mismatch");

  const half8* base = w2p + (size_t)((INS*4)*16 + wv*4)*128 + ln;
  half8 a0=base[0],   a1=base[64];
  half8 a2=base[128], a3=base[192];
  half8 a4=base[256], a5=base[320];
  half8 a6=base[384], a7=base[448];

  #pragma unroll
  for(int uc=0; uc<4; ++uc){
    half8 n0,n1,n2,n3,n4,n5,n6,n7;
    if(uc<3){
      const half8* nb = base + (size_t)(uc+1)*2048;
      n0=nb[0];   n1=nb[64];
      n2=nb[128]; n3=nb[192];
      n4=nb[256]; n5=nb[320];
      n6=nb[384]; n7=nb[448];
    }

    f32x4 yv0[ND3];
    #pragma unroll
    for(int k=0;k<ND3;++k)
      yv0[k]=*(const f32x4*)&yb[eA][k*32 + uc*8 + upb];

    f32x4 z; z[0]=0.f; z[1]=0.f; z[2]=0.f; z[3]=0.f;
    {
      f32x4 c0=__builtin_amdgcn_mfma_f32_16x16x32_f16(a0,hb0,z,0,0,0);
      c0      =__builtin_amdgcn_mfma_f32_16x16x32_f16(a1,hb1,c0,0,0,0);
      #pragma unroll
      for(int k=0;k<ND3;++k)
        p0[0*ND3+k] += c0[0]*yv0[k][0]+c0[1]*yv0[k][1]+c0[2]*yv0[k][2]+c0[3]*yv0[k][3];
    }
    {
      f32x4 c0=__builtin_amdgcn_mfma_f32_16x16x32_f16(a2,hb0,z,0,0,0);
      c0      =__builtin_amdgcn_mfma_f32_16x16x32_f16(a3,hb1,c0,0,0,0);
      #pragma unroll
      for(int k=0;k<ND3;++k)
        p0[1*ND3+k] += c0[0]*yv0[k][0]+c0[1]*yv0[k][1]+c0[2]*yv0[k][2]+c0[3]*yv0[k][3];
    }
    {
      f32x4 c0=__builtin_amdgcn_mfma_f32_16x16x32_f16(a4,hb0,z,0,0,0);
      c0      =__builtin_amdgcn_mfma_f32_16x16x32_f16(a5,hb1,c0,0,0,0);
      #pragma unroll
      for(int k=0;k<ND3;++k)
        p0[2*ND3+k] += c0[0]*yv0[k][0]+c0[1]*yv0[k][1]+c0[2]*yv0[k][2]+c0[3]*yv0[k][3];
    }
    {
      f32x4 c0=__builtin_amdgcn_mfma_f32_16x16x32_f16(a6,hb0,z,0,0,0);
      c0      =__builtin_amdgcn_mfma_f32_16x16x32_f16(a7,hb1,c0,0,0,0);
      #pragma unroll
      for(int k=0;k<ND3;++k)
        p0[3*ND3+k] += c0[0]*yv0[k][0]+c0[1]*yv0[k][1]+c0[2]*yv0[k][2]+c0[3]*yv0[k][3];
    }
    if(uc<3){ a0=n0; a1=n1; a2=n2; a3=n3; a4=n4; a5=n5; a6=n6; a7=n7; }
  }
}

template<int ND3>
__device__ __forceinline__ void flush_set(float* __restrict__ out,
    float* __restrict__ msgbuf, int eg, int d, int E, int OO,
    float pw, int gA, int wsel, int wv, float (&pacc)[4*ND3])
{
  constexpr int KHI=(ND3+1)/2;
  #pragma unroll
  for(int q=0;q<4;++q){
    #pragma unroll
    for(int k=0;k<ND3;++k){
      float p = pacc[q*ND3+k] + __shfl_xor(pacc[q*ND3+k], 16, 64);
      bool mine = (gA&1) ? (k>=KHI) : (k<KHI);
      if(mine && eg<E){
        int w=(wv*4+q)*2+wsel;
        if(msgbuf) msgbuf[(size_t)eg*IND + OO + w*ND3 + k] = pw*p;
        else       atomicAdd(&out[(size_t)d*IND + OO + w*ND3 + k], pw*p);
      }
    }
  }
}

// ---------------- fused MFMA tensor product (r16 schedule, TILE_E=16, af prefetch) ----------------
// grid = 3*ceil(E/16): block bid -> etile=bid/3, l3-group g=bid%3
__global__ __launch_bounds__(256) void tp_kernel(
    const float* __restrict__ x, const int* __restrict__ eidx,
    const float* __restrict__ sh, const _Float16* __restrict__ h16g,
    const _Float16* __restrict__ w2h, const float* __restrict__ w3j,
    float* __restrict__ out, float* __restrict__ msgbuf,
    int E, float pwc0, float pwc1, float pwc2)
{
  __shared__ float shw[2][TILE_E][SHWP];
  __shared__ float ybuf[2][TILE_E][YROW];

  const int t=threadIdx.x;
  const int bid=blockIdx.x;
  const int etile=bid/3, g=bid-etile*3;
  const int e0=etile*TILE_E;

  const int ln=t&63, wv=t>>6;
  const int eA=ln&15, gA=ln>>4;
  const int upb=(gA&1)*4;
  const int wsel=gA>>1;
  const int eg0=e0+eA;

  const int d0 = (eg0<E)? eidx[E+eg0] : -1;

  half8 hb0, hb1;
  #pragma unroll
  for(int i=0;i<8;++i){ hb0[i]=(_Float16)0.f; hb1[i]=(_Float16)0.f; }
  if(eg0<E){
    hb0=*(const half8*)&h16g[(size_t)eg0*64 + gA*8];
    hb1=*(const half8*)&h16g[(size_t)eg0*64 + 32 + gA*8];
  }

  const half8* w2p=(const half8*)w2h;

  if(g==0){
    float p0[4]={};
    b1_step<0>(w3j,sh,shw[0],t,e0,E); __syncthreads();
    b2_step<0>(x,eidx,shw[0],ybuf[0],t,e0,E); b1_step<4>(w3j,sh,shw[1],t,e0,E); __syncthreads();
    comp_step<0,1>(ybuf[0],w2p,hb0,hb1,ln,eA,upb,wv,p0);
    b2_step<4>(x,eidx,shw[1],ybuf[1],t,e0,E); b1_step<9>(w3j,sh,shw[0],t,e0,E); __syncthreads();
    comp_step<4,1>(ybuf[1],w2p,hb0,hb1,ln,eA,upb,wv,p0);
    b2_step<9>(x,eidx,shw[0],ybuf[0],t,e0,E); __syncthreads();
    comp_step<9,1>(ybuf[0],w2p,hb0,hb1,ln,eA,upb,wv,p0);
    flush_set<1>(out,msgbuf,eg0,d0,E,0,pwc0,gA,wsel,wv,p0);
  } else if(g==1){
    float p0[12]={};
    b1_step<1>(w3j,sh,shw[0],t,e0,E); __syncthreads();
    b2_step<1>(x,eidx,shw[0],ybuf[0],t,e0,E); b1_step<3>(w3j,sh,shw[1],t,e0,E); __syncthreads();
    comp_step<1,3>(ybuf[0],w2p,hb0,hb1,ln,eA,upb,wv,p0);
    b2_step<3>(x,eidx,shw[1],ybuf[1],t,e0,E); b1_step<6>(w3j,sh,shw[0],t,e0,E); __syncthreads();
    comp_step<3,3>(ybuf[1],w2p,hb0,hb1,ln,eA,upb,wv,p0);
    b2_step<6>(x,eidx,shw[0],ybuf[0],t,e0,E); b1_step<8>(w3j,sh,shw[1],t,e0,E); __syncthreads();
    comp_step<6,3>(ybuf[0],w2p,hb0,hb1,ln,eA,upb,wv,p0);
    b2_step<8>(x,eidx,shw[1],ybuf[1],t,e0,E); __syncthreads();
    comp_step<8,3>(ybuf[1],w2p,hb0,hb1,ln,eA,upb,wv,p0);
    flush_set<3>(out,msgbuf,eg0,d0,E,32,pwc1,gA,wsel,wv,p0);
  } else {
    float p0[20]={};
    b1_step<2>(w3j,sh,shw[0],t,e0,E); __syncthreads();
    b2_step<2>(x,eidx,shw[0],ybuf[0],t,e0,E); b1_step<5>(w3j,sh,shw[1],t,e0,E); __syncthreads();
    comp_step<2,5>(ybuf[0],w2p,hb0,hb1,ln,eA,upb,wv,p0);
    b2_step<5>(x,eidx,shw[1],ybuf[1],t,e0,E); b1_step<7>(w3j,sh,shw[0],t,e0,E); __syncthreads();
    comp_step<5,5>(ybuf[1],w2p,hb0,hb1,ln,eA,upb,wv,p0);
    b2_step<7>(x,eidx,shw[0],ybuf[0],t,e0,E); b1_step<10>(w3j,sh,shw[1],t,e0,E); __syncthreads();
    comp_step<7,5>(ybuf[0],w2p,hb0,hb1,ln,eA,upb,wv,p0);
    b2_step<10>(x,eidx,shw[1],ybuf[1],t,e0,E); __syncthreads();
    comp_step<10,5>(ybuf[1],w2p,hb0,hb1,ln,eA,upb,wv,p0);
    flush_set<5>(out,msgbuf,eg0,d0,E,128,pwc2,gA,wsel,wv,p0);
  }
}

extern "C" void kernel_launch(void* const* d_in, const int* in_sizes, int n_in,
                              void* d_out, int out_size, void* d_ws, size_t ws_size,
                              hipStream_t stream){
  const float* x     =(const float*)d_in[0];
  const int*   eidx  =(const int*)  d_in[1];
  const float* sh    =(const float*)d_in[2];
  const float* radial=(const float*)d_in[3];
  const float* W1    =(const float*)d_in[4];
  const float* W2    =(const float*)d_in[5];
  const float* Wsc0  =(const float*)d_in[6];
  const float* Wsc1  =(const float*)d_in[7];
  const float* Wsc2  =(const float*)d_in[8];
  float* out=(float*)d_out;
  int n_nodes=in_sizes[0]/IND;
  int E=in_sizes[1]/2;

  float inv10=1.0f/sqrtf(10.0f);
  float pwc0=sqrtf(1.0f/96.0f) *0.125f*inv10;
  float pwc1=sqrtf(3.0f/128.0f)*0.125f*inv10;
  float pwc2=sqrtf(5.0f/128.0f)*0.125f*inv10;
  float silu_cst=1.67682f;

  // workspace layout
  size_t off=0;
  auto alloc=[&](size_t bytes)->size_t{ size_t o=off; off=(off+bytes+255)&~(size_t)255; return o; };
  size_t o_w3j = alloc(2048);
  size_t o_w2h = alloc((size_t)704*2*64*8*2);          // 1.44 MB f16
  size_t o_h16 = alloc((size_t)E*64*2);                // 2.56 MB f16
  size_t o_row = alloc((size_t)(n_nodes+64)*4);
  size_t o_eli = alloc((size_t)E*4);
  size_t o_msg = alloc((size_t)E*IND*4);               // 23 MB
  bool use_msg = (off <= ws_size) && (n_nodes <= 2048);

  char* ws=(char*)d_ws;
  float*     w3j =(float*)(ws+o_w3j);
  _Float16*  w2h =(_Float16*)(ws+o_w2h);
  _Float16*  h16g=(_Float16*)(ws+o_h16);
  int*       row =(int*)(ws+o_row);
  int*       eli =(int*)(ws+o_eli);
  float*     msg =(float*)(ws+o_msg);

  int ntile=(E+TILE_E-1)/TILE_E;
  int hblocks=(E*64+255)/256;
  int prep_blocks = NINS+352+hblocks + (use_msg?1:0);

  hipLaunchKernelGGL(prep_kernel, dim3(prep_blocks), dim3(256), 0, stream,
                     w3j, W2, w2h, radial, W1, h16g, E, silu_cst,
                     eidx, row, eli, n_nodes, hblocks);

  if(use_msg){
    hipLaunchKernelGGL(tp_kernel, dim3(3*ntile), dim3(256), 0, stream,
                       x, eidx, sh, h16g, w2h, w3j, out, msg, E, pwc0, pwc1, pwc2);
    hipLaunchKernelGGL(gather_kernel, dim3(n_nodes), dim3(256), 0, stream,
                       msg, row, eli, x, Wsc0, Wsc1, Wsc2, out, n_nodes);
  } else {
    hipLaunchKernelGGL(sc_kernel, dim3(n_nodes), dim3(256), 0, stream,
                       x, Wsc0, Wsc1, Wsc2, out, n_nodes);
    hipLaunchKernelGGL(tp_kernel, dim3(3*ntile), dim3(256), 0, stream,
                       x, eidx, sh, h16g, w2h, w3j, out, (float*)nullptr, E, pwc0, pwc1, pwc2);
  }
}

// Round 18
// 266.905 us; speedup vs baseline: 1.6984x; 1.6984x over previous
//
#include <hip/hip_runtime.h>
#include <math.h>

#define TILE_E 16
#define NINS 11
#define IND 288
#define SHD 9
#define W2N 11264
#define YROW 164    // ybuf row stride (f32): (164e)%32=4e -> b128 reads 2-way (free)
#define SHWP 28     // shw row pad

typedef _Float16 half8 __attribute__((ext_vector_type(8)));
typedef float f32x4 __attribute__((ext_vector_type(4)));

constexpr int kL1[NINS] = {0,0,0,1,1,1,1,2,2,2,2};
constexpr int kL2[NINS] = {0,1,2,0,1,1,2,0,1,2,2};
constexpr int kL3[NINS] = {0,1,2,1,0,2,1,2,1,0,2};
constexpr int kW3OFF[NINS] = {0,1,10,35,44,53,98,143,168,213,238};

// ---------------- Wigner 3j (exact port of reference) ----------------
__device__ double dfac(int n){ double r=1.0; for(int i=2;i<=n;++i) r*=(double)i; return r; }

__device__ void qmat_dev(int l,double* qr,double* qi){
  int d=2*l+1;
  for(int i=0;i<d*d;++i){qr[i]=0.0;qi[i]=0.0;}
  const double s=0.70710678118654752440;
  for(int m=-l;m<0;++m){
    qr[(l+m)*d+(l-m)]=s;
    qi[(l+m)*d+(l+m)]=-s;
  }
  qr[l*d+l]=1.0;
  for(int m=1;m<=l;++m){
    double sg=(m&1)?-1.0:1.0;
    qr[(l+m)*d+(l+m)]=sg*s;
    qi[(l+m)*d+(l-m)]=sg*s;
  }
  if(l==1){ for(int i=0;i<d*d;++i){ double a=qr[i],b=qi[i]; qr[i]=b; qi[i]=-a; } }
  else if(l==2){ for(int i=0;i<d*d;++i){ qr[i]=-qr[i]; qi[i]=-qi[i]; } }
}

__device__ void w3j_body(int ins, int t, float* w3j){
  const int l1=kL1[ins],l2=kL2[ins],l3=kL3[ins];
  const int d1=2*l1+1,d2=2*l2+1,d3=2*l3+1;
  const int n=d1*d2*d3;

  __shared__ double C[125];
  __shared__ double R[125];
  __shared__ double q1r[25],q1i[25],q2r[25],q2i[25],q3r[25],q3i[25];
  __shared__ double inv;

  for(int i=t;i<125;i+=256) C[i]=0.0;
  if(t==0){
    qmat_dev(l1,q1r,q1i); qmat_dev(l2,q2r,q2i); qmat_dev(l3,q3r,q3i);
  }
  __syncthreads();

  if(t<d1*d2){
    int m1=t/d2-l1, m2=t-(t/d2)*d2-l2;
    int m3=m1+m2;
    if(m3>=-l3 && m3<=l3){
      int vmin=-l1+l2+m3; if(-l1+m1>vmin)vmin=-l1+m1; if(0>vmin)vmin=0;
      int vmax=l2+l3+m1; if(l3-l1+l2<vmax)vmax=l3-l1+l2; if(l3+m3<vmax)vmax=l3+m3;
      double c=sqrt((double)(2*l3+1)*dfac(l3+l1-l2)*dfac(l3-l1+l2)*dfac(l1+l2-l3)
        *dfac(l3+m3)*dfac(l3-m3)
        /(dfac(l1+l2+l3+1)*dfac(l1-m1)*dfac(l1+m1)*dfac(l2-m2)*dfac(l2+m2)));
      double s=0.0;
      for(int v=vmin;v<=vmax;++v){
        double term=dfac(l2+l3+m1-v)*dfac(l1-m1+v)
          /(dfac(v)*dfac(l3-l1+l2-v)*dfac(l3+m3-v)*dfac(v+l1-l2-m3));
        s += (((v+l2+m2)&1)?-1.0:1.0)*term;
      }
      C[((m1+l1)*d2+(m2+l2))*d3+(m3+l3)]=c*s;
    }
  }
  __syncthreads();

  if(t<n){
    int j=t/(d2*d3);
    int rem=t-j*(d2*d3);
    int l=rem/d3, m=rem-l*d3;
    double sr=0.0;
    for(int a=0;a<d1;++a)for(int b=0;b<d2;++b)for(int nn=0;nn<d3;++nn){
      double cv=C[(a*d2+b)*d3+nn];
      if(cv==0.0) continue;
      double xr=q1r[a*d1+j],xi=q1i[a*d1+j];
      double yr=q2r[b*d2+l],yi=q2i[b*d2+l];
      double zr=q3r[nn*d3+m],zi=-q3i[nn*d3+m];
      double pr=xr*yr-xi*yi, pi=xr*yi+xi*yr;
      sr += (pr*zr-pi*zi)*cv;
    }
    R[t]=sr;
  }
  __syncthreads();
  if(t==0){
    double n2=0.0;
    for(int i=0;i<n;++i) n2+=R[i]*R[i];
    inv=1.0/sqrt(n2);
  }
  __syncthreads();
  if(t<n) w3j[kW3OFF[ins]+t]=(float)(R[t]*inv);
}

__device__ void pack_body(int pb, int t, const float* __restrict__ W2,
                          _Float16* __restrict__ w2h){
  int q = pb*256 + t;                        // 704*2*64 = 90112
  if(q >= 704*2*64) return;
  int l = q & 63;
  int s = (q>>6)&1;
  int g = q>>7;
  int ins=g>>6, rem=g&63, uc=rem>>4, tp=rem&15;
  int m = l&15;
  int col = ins*1024 + (uc*8 + (m&7))*32 + tp*2 + (m>>3);
  int c0  = s*32 + ((l>>4)<<3);
  half8 v;
  #pragma unroll
  for(int i=0;i<8;++i) v[i] = (_Float16)W2[(size_t)(c0+i)*W2N + col];
  *(half8*)&w2h[(size_t)q*8] = v;
}

__device__ void h_body(int hb, int t, const float* __restrict__ radial,
    const float* __restrict__ W1, _Float16* __restrict__ h16g, int E, float silu_cst){
  int idx = hb*256 + t;
  int e = idx>>6, c = idx&63;
  if(e>=E) return;
  const float* rr = radial + (size_t)e*64;
  float acc=0.f;
  #pragma unroll 8
  for(int r=0;r<64;++r) acc += rr[r]*W1[r*64+c];
  acc*=0.125f;
  float hv = silu_cst*acc/(1.f+expf(-acc));
  h16g[idx]=(_Float16)hv;
}

// CSR hist + scan + fill in one block (n <= 2048)
__device__ void csr_body(int t, const int* __restrict__ eidx,
    int* __restrict__ rowptr, int* __restrict__ elist, int E, int n){
  __shared__ int deg[2048];
  __shared__ int psum[256];
  for(int i=t;i<2048;i+=256) deg[i]=0;
  __syncthreads();
  for(int e=t;e<E;e+=256) atomicAdd(&deg[eidx[E+e]],1);
  __syncthreads();
  int base=t*8;
  int loc[8]; int s=0;
  #pragma unroll
  for(int i=0;i<8;++i){ loc[i]=(base+i<n)?deg[base+i]:0; s+=loc[i]; }
  psum[t]=s;
  __syncthreads();
  for(int off=1; off<256; off<<=1){
    int v=psum[t];
    int add=(t>=off)?psum[t-off]:0;
    __syncthreads();
    psum[t]=v+add;
    __syncthreads();
  }
  int excl=psum[t]-s;
  #pragma unroll
  for(int i=0;i<8;++i){
    if(base+i<n){ rowptr[base+i]=excl; deg[base+i]=excl; }  // deg becomes LDS cursor
    excl+=loc[i];
  }
  if(t==255) rowptr[n]=psum[255];
  __syncthreads();
  for(int e=t;e<E;e+=256){
    int d=eidx[E+e];
    int pos=atomicAdd(&deg[d],1);
    elist[pos]=e;
  }
}

// one launch: [0,11)=w3j, [11,363)=pack_w2, [363,363+hblocks)=h, optional last=csr(+fill)
__global__ __launch_bounds__(256) void prep_kernel(float* w3j,
    const float* __restrict__ W2, _Float16* __restrict__ w2h,
    const float* __restrict__ radial, const float* __restrict__ W1,
    _Float16* __restrict__ h16g, int E, float silu_cst,
    const int* __restrict__ eidx, int* __restrict__ rowptr, int* __restrict__ elist,
    int n_nodes, int hblocks){
  int b=blockIdx.x, t=threadIdx.x;
  if(b<NINS)                  w3j_body(b, t, w3j);
  else if(b<NINS+352)         pack_body(b-NINS, t, W2, w2h);
  else if(b<NINS+352+hblocks) h_body(b-NINS-352, t, radial, W1, h16g, E, silu_cst);
  else                        csr_body(t, eidx, rowptr, elist, E, n_nodes);
}

// ---------------- gather + fused self-connection ----------------
__global__ __launch_bounds__(256) void gather_kernel(const float* __restrict__ msgbuf,
    const int* __restrict__ rowptr, const int* __restrict__ elist,
    const float* __restrict__ x,
    const float* __restrict__ W0, const float* __restrict__ W1s, const float* __restrict__ W2s,
    float* __restrict__ out, int n_nodes)
{
  int n=blockIdx.x;
  if(n>=n_nodes) return;
  int s0=rowptr[n], s1=rowptr[n+1];
  const float inv=0.17677669529663689f;  // 1/sqrt(32)
  for(int o=threadIdx.x; o<IND; o+=blockDim.x){
    float acc=0.f;
    for(int j=s0;j<s1;++j)
      acc += msgbuf[(size_t)elist[j]*IND + o];
    const float* W; int w,k,d,xo;
    if(o<32){W=W0; w=o; k=0; d=1; xo=0;}
    else if(o<128){int r=o-32; W=W1s; d=3; w=r/3; k=r-w*3; xo=32;}
    else {int r=o-128; W=W2s; d=5; w=r/5; k=r-w*5; xo=128;}
    float ssc=0.f;
    const float* xr=x+(size_t)n*IND+xo+k;
    for(int u=0;u<32;++u) ssc += xr[u*d]*W[u*32+w];
    out[(size_t)n*IND+o]=acc + ssc*inv;
  }
}

// ---------------- self connection (fallback path only) ----------------
__global__ __launch_bounds__(256) void sc_kernel(const float* __restrict__ x,
  const float* __restrict__ W0, const float* __restrict__ W1s, const float* __restrict__ W2s,
  float* __restrict__ out, int n_nodes)
{
  int n=blockIdx.x;
  if(n>=n_nodes) return;
  const float inv=0.17677669529663689f;
  for(int o=threadIdx.x; o<IND; o+=blockDim.x){
    const float* W; int w,k,d,xo;
    if(o<32){W=W0; w=o; k=0; d=1; xo=0;}
    else if(o<128){int r=o-32; W=W1s; d=3; w=r/3; k=r-w*3; xo=32;}
    else {int r=o-128; W=W2s; d=5; w=r/5; k=r-w*5; xo=128;}
    float s=0.f;
    const float* xr=x+(size_t)n*IND+xo+k;
    for(int u=0;u<32;++u) s += xr[u*d]*W[u*32+w];
    out[(size_t)n*IND+o]=s*inv;
  }
}

// ---------------- tp building blocks ----------------
template<int INS>
__device__ __forceinline__ void b1_step(const float* __restrict__ w3j,
    const float* __restrict__ sh, float (*shw)[SHWP], int t, int e0, int E)
{
  constexpr int L1v=kL1[INS], L2v=kL2[INS];
  constexpr int D1=2*L1v+1, D2=2*L2v+1, D3=2*kL3[INS]+1;
  constexpr int SO=(L2v==0)?0:(L2v==1?1:4);
  const float* w3=w3j+kW3OFF[INS];
  constexpr int NN=TILE_E*D1*D3;
  for(int idx=t; idx<NN; idx+=256){
    int e=idx/(D1*D3), r=idx-e*(D1*D3);
    int i=r/D3, k=r-i*D3;
    int eg=e0+e;
    float s=0.f;
    if(eg<E){
      #pragma unroll
      for(int j=0;j<D2;++j) s += w3[(i*D2+j)*D3+k]*sh[(size_t)eg*SHD+SO+j];
    }
    shw[e][r]=s;
  }
}

template<int INS>
__device__ __forceinline__ void b2_step(const float* __restrict__ x,
    const int* __restrict__ eidx, const float (*shw)[SHWP], float (*yb)[YROW],
    int t, int e0, int E)
{
  constexpr int L1v=kL1[INS];
  constexpr int D1=2*L1v+1, D3=2*kL3[INS]+1;
  constexpr int XO=(L1v==0)?0:(L1v==1?32:128);
  constexpr int NN=TILE_E*32*D3;
  for(int idx=t; idx<NN; idx+=256){
    int e=idx/(32*D3), r=idx-e*(32*D3);
    int k=r>>5, u=r&31;
    int eg=e0+e;
    float s=0.f;
    if(eg<E){
      int srn=eidx[eg];
      const float* xr=x+(size_t)srn*IND+XO+u*D1;
      #pragma unroll
      for(int i=0;i<D1;++i) s += shw[e][i*D3+k]*xr[i];
    }
    yb[e][k*32+u]=s;
  }
}

// compute phase: runtime uc loop (no unroll) with depth-1 af register prefetch (r12 form)
template<int INS, int ND3>
__device__ __forceinline__ void comp_step(const float (*yb)[YROW],
    const half8* __restrict__ w2p,
    half8 hb0, half8 hb1,
    int ln, int eA, int upb, int wv,
    float (&p0)[4*ND3])
{
  constexpr int D3=2*kL3[INS]+1;
  static_assert(D3==ND3, "group/ins D3 mismatch");

  const half8* base = w2p + (size_t)((INS*4)*16 + wv*4)*128 + ln;
  half8 a0=base[0],   a1=base[64];
  half8 a2=base[128], a3=base[192];
  half8 a4=base[256], a5=base[320];
  half8 a6=base[384], a7=base[448];

  #pragma unroll 1
  for(int uc=0; uc<4; ++uc){
    half8 b0,b1,b2,b3,b4,b5,b6,b7;
    const bool pf = (uc<3);
    if(pf){
      const half8* nb = base + (size_t)(uc+1)*2048;
      b0=nb[0];   b1=nb[64];
      b2=nb[128]; b3=nb[192];
      b4=nb[256]; b5=nb[320];
      b6=nb[384]; b7=nb[448];
    }

    f32x4 yv0[ND3];
    #pragma unroll
    for(int k=0;k<ND3;++k)
      yv0[k]=*(const f32x4*)&yb[eA][k*32 + uc*8 + upb];

    f32x4 z; z[0]=0.f; z[1]=0.f; z[2]=0.f; z[3]=0.f;
    {
      f32x4 c0=__builtin_amdgcn_mfma_f32_16x16x32_f16(a0,hb0,z,0,0,0);
      c0      =__builtin_amdgcn_mfma_f32_16x16x32_f16(a1,hb1,c0,0,0,0);
      #pragma unroll
      for(int k=0;k<ND3;++k)
        p0[0*ND3+k] += c0[0]*yv0[k][0]+c0[1]*yv0[k][1]+c0[2]*yv0[k][2]+c0[3]*yv0[k][3];
    }
    {
      f32x4 c0=__builtin_amdgcn_mfma_f32_16x16x32_f16(a2,hb0,z,0,0,0);
      c0      =__builtin_amdgcn_mfma_f32_16x16x32_f16(a3,hb1,c0,0,0,0);
      #pragma unroll
      for(int k=0;k<ND3;++k)
        p0[1*ND3+k] += c0[0]*yv0[k][0]+c0[1]*yv0[k][1]+c0[2]*yv0[k][2]+c0[3]*yv0[k][3];
    }
    {
      f32x4 c0=__builtin_amdgcn_mfma_f32_16x16x32_f16(a4,hb0,z,0,0,0);
      c0      =__builtin_amdgcn_mfma_f32_16x16x32_f16(a5,hb1,c0,0,0,0);
      #pragma unroll
      for(int k=0;k<ND3;++k)
        p0[2*ND3+k] += c0[0]*yv0[k][0]+c0[1]*yv0[k][1]+c0[2]*yv0[k][2]+c0[3]*yv0[k][3];
    }
    {
      f32x4 c0=__builtin_amdgcn_mfma_f32_16x16x32_f16(a6,hb0,z,0,0,0);
      c0      =__builtin_amdgcn_mfma_f32_16x16x32_f16(a7,hb1,c0,0,0,0);
      #pragma unroll
      for(int k=0;k<ND3;++k)
        p0[3*ND3+k] += c0[0]*yv0[k][0]+c0[1]*yv0[k][1]+c0[2]*yv0[k][2]+c0[3]*yv0[k][3];
    }
    if(pf){ a0=b0; a1=b1; a2=b2; a3=b3; a4=b4; a5=b5; a6=b6; a7=b7; }
  }
}

template<int ND3>
__device__ __forceinline__ void flush_set(float* __restrict__ out,
    float* __restrict__ msgbuf, int eg, int d, int E, int OO,
    float pw, int gA, int wsel, int wv, float (&pacc)[4*ND3])
{
  constexpr int KHI=(ND3+1)/2;
  #pragma unroll
  for(int q=0;q<4;++q){
    #pragma unroll
    for(int k=0;k<ND3;++k){
      float p = pacc[q*ND3+k] + __shfl_xor(pacc[q*ND3+k], 16, 64);
      bool mine = (gA&1) ? (k>=KHI) : (k<KHI);
      if(mine && eg<E){
        int w=(wv*4+q)*2+wsel;
        if(msgbuf) msgbuf[(size_t)eg*IND + OO + w*ND3 + k] = pw*p;
        else       atomicAdd(&out[(size_t)d*IND + OO + w*ND3 + k], pw*p);
      }
    }
  }
}

// ---------------- fused MFMA tensor product (r16 schedule, TILE_E=16, runtime-loop prefetch) ----------------
// grid = 3*ceil(E/16): block bid -> etile=bid/3, l3-group g=bid%3
__global__ __launch_bounds__(256) void tp_kernel(
    const float* __restrict__ x, const int* __restrict__ eidx,
    const float* __restrict__ sh, const _Float16* __restrict__ h16g,
    const _Float16* __restrict__ w2h, const float* __restrict__ w3j,
    float* __restrict__ out, float* __restrict__ msgbuf,
    int E, float pwc0, float pwc1, float pwc2)
{
  __shared__ float shw[2][TILE_E][SHWP];
  __shared__ float ybuf[2][TILE_E][YROW];

  const int t=threadIdx.x;
  const int bid=blockIdx.x;
  const int etile=bid/3, g=bid-etile*3;
  const int e0=etile*TILE_E;

  const int ln=t&63, wv=t>>6;
  const int eA=ln&15, gA=ln>>4;
  const int upb=(gA&1)*4;
  const int wsel=gA>>1;
  const int eg0=e0+eA;

  const int d0 = (eg0<E)? eidx[E+eg0] : -1;

  half8 hb0, hb1;
  #pragma unroll
  for(int i=0;i<8;++i){ hb0[i]=(_Float16)0.f; hb1[i]=(_Float16)0.f; }
  if(eg0<E){
    hb0=*(const half8*)&h16g[(size_t)eg0*64 + gA*8];
    hb1=*(const half8*)&h16g[(size_t)eg0*64 + 32 + gA*8];
  }

  const half8* w2p=(const half8*)w2h;

  if(g==0){
    float p0[4]={};
    b1_step<0>(w3j,sh,shw[0],t,e0,E); __syncthreads();
    b2_step<0>(x,eidx,shw[0],ybuf[0],t,e0,E); b1_step<4>(w3j,sh,shw[1],t,e0,E); __syncthreads();
    comp_step<0,1>(ybuf[0],w2p,hb0,hb1,ln,eA,upb,wv,p0);
    b2_step<4>(x,eidx,shw[1],ybuf[1],t,e0,E); b1_step<9>(w3j,sh,shw[0],t,e0,E); __syncthreads();
    comp_step<4,1>(ybuf[1],w2p,hb0,hb1,ln,eA,upb,wv,p0);
    b2_step<9>(x,eidx,shw[0],ybuf[0],t,e0,E); __syncthreads();
    comp_step<9,1>(ybuf[0],w2p,hb0,hb1,ln,eA,upb,wv,p0);
    flush_set<1>(out,msgbuf,eg0,d0,E,0,pwc0,gA,wsel,wv,p0);
  } else if(g==1){
    float p0[12]={};
    b1_step<1>(w3j,sh,shw[0],t,e0,E); __syncthreads();
    b2_step<1>(x,eidx,shw[0],ybuf[0],t,e0,E); b1_step<3>(w3j,sh,shw[1],t,e0,E); __syncthreads();
    comp_step<1,3>(ybuf[0],w2p,hb0,hb1,ln,eA,upb,wv,p0);
    b2_step<3>(x,eidx,shw[1],ybuf[1],t,e0,E); b1_step<6>(w3j,sh,shw[0],t,e0,E); __syncthreads();
    comp_step<3,3>(ybuf[1],w2p,hb0,hb1,ln,eA,upb,wv,p0);
    b2_step<6>(x,eidx,shw[0],ybuf[0],t,e0,E); b1_step<8>(w3j,sh,shw[1],t,e0,E); __syncthreads();
    comp_step<6,3>(ybuf[0],w2p,hb0,hb1,ln,eA,upb,wv,p0);
    b2_step<8>(x,eidx,shw[1],ybuf[1],t,e0,E); __syncthreads();
    comp_step<8,3>(ybuf[1],w2p,hb0,hb1,ln,eA,upb,wv,p0);
    flush_set<3>(out,msgbuf,eg0,d0,E,32,pwc1,gA,wsel,wv,p0);
  } else {
    float p0[20]={};
    b1_step<2>(w3j,sh,shw[0],t,e0,E); __syncthreads();
    b2_step<2>(x,eidx,shw[0],ybuf[0],t,e0,E); b1_step<5>(w3j,sh,shw[1],t,e0,E); __syncthreads();
    comp_step<2,5>(ybuf[0],w2p,hb0,hb1,ln,eA,upb,wv,p0);
    b2_step<5>(x,eidx,shw[1],ybuf[1],t,e0,E); b1_step<7>(w3j,sh,shw[0],t,e0,E); __syncthreads();
    comp_step<5,5>(ybuf[1],w2p,hb0,hb1,ln,eA,upb,wv,p0);
    b2_step<7>(x,eidx,shw[0],ybuf[0],t,e0,E); b1_step<10>(w3j,sh,shw[1],t,e0,E); __syncthreads();
    comp_step<7,5>(ybuf[0],w2p,hb0,hb1,ln,eA,upb,wv,p0);
    b2_step<10>(x,eidx,shw[1],ybuf[1],t,e0,E); __syncthreads();
    comp_step<10,5>(ybuf[1],w2p,hb0,hb1,ln,eA,upb,wv,p0);
    flush_set<5>(out,msgbuf,eg0,d0,E,128,pwc2,gA,wsel,wv,p0);
  }
}

extern "C" void kernel_launch(void* const* d_in, const int* in_sizes, int n_in,
                              void* d_out, int out_size, void* d_ws, size_t ws_size,
                              hipStream_t stream){
  const float* x     =(const float*)d_in[0];
  const int*   eidx  =(const int*)  d_in[1];
  const float* sh    =(const float*)d_in[2];
  const float* radial=(const float*)d_in[3];
  const float* W1    =(const float*)d_in[4];
  const float* W2    =(const float*)d_in[5];
  const float* Wsc0  =(const float*)d_in[6];
  const float* Wsc1  =(const float*)d_in[7];
  const float* Wsc2  =(const float*)d_in[8];
  float* out=(float*)d_out;
  int n_nodes=in_sizes[0]/IND;
  int E=in_sizes[1]/2;

  float inv10=1.0f/sqrtf(10.0f);
  float pwc0=sqrtf(1.0f/96.0f) *0.125f*inv10;
  float pwc1=sqrtf(3.0f/128.0f)*0.125f*inv10;
  float pwc2=sqrtf(5.0f/128.0f)*0.125f*inv10;
  float silu_cst=1.67682f;

  // workspace layout
  size_t off=0;
  auto alloc=[&](size_t bytes)->size_t{ size_t o=off; off=(off+bytes+255)&~(size_t)255; return o; };
  size_t o_w3j = alloc(2048);
  size_t o_w2h = alloc((size_t)704*2*64*8*2);          // 1.44 MB f16
  size_t o_h16 = alloc((size_t)E*64*2);                // 2.56 MB f16
  size_t o_row = alloc((size_t)(n_nodes+64)*4);
  size_t o_eli = alloc((size_t)E*4);
  size_t o_msg = alloc((size_t)E*IND*4);               // 23 MB
  bool use_msg = (off <= ws_size) && (n_nodes <= 2048);

  char* ws=(char*)d_ws;
  float*     w3j =(float*)(ws+o_w3j);
  _Float16*  w2h =(_Float16*)(ws+o_w2h);
  _Float16*  h16g=(_Float16*)(ws+o_h16);
  int*       row =(int*)(ws+o_row);
  int*       eli =(int*)(ws+o_eli);
  float*     msg =(float*)(ws+o_msg);

  int ntile=(E+TILE_E-1)/TILE_E;
  int hblocks=(E*64+255)/256;
  int prep_blocks = NINS+352+hblocks + (use_msg?1:0);

  hipLaunchKernelGGL(prep_kernel, dim3(prep_blocks), dim3(256), 0, stream,
                     w3j, W2, w2h, radial, W1, h16g, E, silu_cst,
                     eidx, row, eli, n_nodes, hblocks);

  if(use_msg){
    hipLaunchKernelGGL(tp_kernel, dim3(3*ntile), dim3(256), 0, stream,
                       x, eidx, sh, h16g, w2h, w3j, out, msg, E, pwc0, pwc1, pwc2);
    hipLaunchKernelGGL(gather_kernel, dim3(n_nodes), dim3(256), 0, stream,
                       msg, row, eli, x, Wsc0, Wsc1, Wsc2, out, n_nodes);
  } else {
    hipLaunchKernelGGL(sc_kernel, dim3(n_nodes), dim3(256), 0, stream,
                       x, Wsc0, Wsc1, Wsc2, out, n_nodes);
    hipLaunchKernelGGL(tp_kernel, dim3(3*ntile), dim3(256), 0, stream,
                       x, eidx, sh, h16g, w2h, w3j, out, (float*)nullptr, E, pwc0, pwc1, pwc2);
  }
}

// Round 19
// 216.022 us; speedup vs baseline: 2.0985x; 1.2355x over previous
//
#include <hip/hip_runtime.h>
#include <math.h>

#define TILE_E 16
#define NINS 11
#define IND 288
#define SHD 9
#define W2N 11264
#define YROW 164    // ybuf row stride (f32): (164e)%32=4e -> b128 reads 2-way (free)
#define SHWP 28     // shw row pad

typedef _Float16 half8 __attribute__((ext_vector_type(8)));
typedef float f32x4 __attribute__((ext_vector_type(4)));

constexpr int kL1[NINS] = {0,0,0,1,1,1,1,2,2,2,2};
constexpr int kL2[NINS] = {0,1,2,0,1,1,2,0,1,2,2};
constexpr int kL3[NINS] = {0,1,2,1,0,2,1,2,1,0,2};
constexpr int kW3OFF[NINS] = {0,1,10,35,44,53,98,143,168,213,238};

// ---------------- Wigner 3j (exact port of reference) ----------------
__device__ double dfac(int n){ double r=1.0; for(int i=2;i<=n;++i) r*=(double)i; return r; }

__device__ void qmat_dev(int l,double* qr,double* qi){
  int d=2*l+1;
  for(int i=0;i<d*d;++i){qr[i]=0.0;qi[i]=0.0;}
  const double s=0.70710678118654752440;
  for(int m=-l;m<0;++m){
    qr[(l+m)*d+(l-m)]=s;
    qi[(l+m)*d+(l+m)]=-s;
  }
  qr[l*d+l]=1.0;
  for(int m=1;m<=l;++m){
    double sg=(m&1)?-1.0:1.0;
    qr[(l+m)*d+(l+m)]=sg*s;
    qi[(l+m)*d+(l-m)]=sg*s;
  }
  if(l==1){ for(int i=0;i<d*d;++i){ double a=qr[i],b=qi[i]; qr[i]=b; qi[i]=-a; } }
  else if(l==2){ for(int i=0;i<d*d;++i){ qr[i]=-qr[i]; qi[i]=-qi[i]; } }
}

__device__ void w3j_body(int ins, int t, float* w3j){
  const int l1=kL1[ins],l2=kL2[ins],l3=kL3[ins];
  const int d1=2*l1+1,d2=2*l2+1,d3=2*l3+1;
  const int n=d1*d2*d3;

  __shared__ double C[125];
  __shared__ double R[125];
  __shared__ double q1r[25],q1i[25],q2r[25],q2i[25],q3r[25],q3i[25];
  __shared__ double inv;

  for(int i=t;i<125;i+=256) C[i]=0.0;
  if(t==0){
    qmat_dev(l1,q1r,q1i); qmat_dev(l2,q2r,q2i); qmat_dev(l3,q3r,q3i);
  }
  __syncthreads();

  if(t<d1*d2){
    int m1=t/d2-l1, m2=t-(t/d2)*d2-l2;
    int m3=m1+m2;
    if(m3>=-l3 && m3<=l3){
      int vmin=-l1+l2+m3; if(-l1+m1>vmin)vmin=-l1+m1; if(0>vmin)vmin=0;
      int vmax=l2+l3+m1; if(l3-l1+l2<vmax)vmax=l3-l1+l2; if(l3+m3<vmax)vmax=l3+m3;
      double c=sqrt((double)(2*l3+1)*dfac(l3+l1-l2)*dfac(l3-l1+l2)*dfac(l1+l2-l3)
        *dfac(l3+m3)*dfac(l3-m3)
        /(dfac(l1+l2+l3+1)*dfac(l1-m1)*dfac(l1+m1)*dfac(l2-m2)*dfac(l2+m2)));
      double s=0.0;
      for(int v=vmin;v<=vmax;++v){
        double term=dfac(l2+l3+m1-v)*dfac(l1-m1+v)
          /(dfac(v)*dfac(l3-l1+l2-v)*dfac(l3+m3-v)*dfac(v+l1-l2-m3));
        s += (((v+l2+m2)&1)?-1.0:1.0)*term;
      }
      C[((m1+l1)*d2+(m2+l2))*d3+(m3+l3)]=c*s;
    }
  }
  __syncthreads();

  if(t<n){
    int j=t/(d2*d3);
    int rem=t-j*(d2*d3);
    int l=rem/d3, m=rem-l*d3;
    double sr=0.0;
    for(int a=0;a<d1;++a)for(int b=0;b<d2;++b)for(int nn=0;nn<d3;++nn){
      double cv=C[(a*d2+b)*d3+nn];
      if(cv==0.0) continue;
      double xr=q1r[a*d1+j],xi=q1i[a*d1+j];
      double yr=q2r[b*d2+l],yi=q2i[b*d2+l];
      double zr=q3r[nn*d3+m],zi=-q3i[nn*d3+m];
      double pr=xr*yr-xi*yi, pi=xr*yi+xi*yr;
      sr += (pr*zr-pi*zi)*cv;
    }
    R[t]=sr;
  }
  __syncthreads();
  if(t==0){
    double n2=0.0;
    for(int i=0;i<n;++i) n2+=R[i]*R[i];
    inv=1.0/sqrt(n2);
  }
  __syncthreads();
  if(t<n) w3j[kW3OFF[ins]+t]=(float)(R[t]*inv);
}

__device__ void pack_body(int pb, int t, const float* __restrict__ W2,
                          _Float16* __restrict__ w2h){
  int q = pb*256 + t;                        // 704*2*64 = 90112
  if(q >= 704*2*64) return;
  int l = q & 63;
  int s = (q>>6)&1;
  int g = q>>7;
  int ins=g>>6, rem=g&63, uc=rem>>4, tp=rem&15;
  int m = l&15;
  int col = ins*1024 + (uc*8 + (m&7))*32 + tp*2 + (m>>3);
  int c0  = s*32 + ((l>>4)<<3);
  half8 v;
  #pragma unroll
  for(int i=0;i<8;++i) v[i] = (_Float16)W2[(size_t)(c0+i)*W2N + col];
  *(half8*)&w2h[(size_t)q*8] = v;
}

__device__ void h_body(int hb, int t, const float* __restrict__ radial,
    const float* __restrict__ W1, _Float16* __restrict__ h16g, int E, float silu_cst){
  int idx = hb*256 + t;
  int e = idx>>6, c = idx&63;
  if(e>=E) return;
  const float* rr = radial + (size_t)e*64;
  float acc=0.f;
  #pragma unroll 8
  for(int r=0;r<64;++r) acc += rr[r]*W1[r*64+c];
  acc*=0.125f;
  float hv = silu_cst*acc/(1.f+expf(-acc));
  h16g[idx]=(_Float16)hv;
}

// CSR hist + scan + fill in one block (n <= 2048)
__device__ void csr_body(int t, const int* __restrict__ eidx,
    int* __restrict__ rowptr, int* __restrict__ elist, int E, int n){
  __shared__ int deg[2048];
  __shared__ int psum[256];
  for(int i=t;i<2048;i+=256) deg[i]=0;
  __syncthreads();
  for(int e=t;e<E;e+=256) atomicAdd(&deg[eidx[E+e]],1);
  __syncthreads();
  int base=t*8;
  int loc[8]; int s=0;
  #pragma unroll
  for(int i=0;i<8;++i){ loc[i]=(base+i<n)?deg[base+i]:0; s+=loc[i]; }
  psum[t]=s;
  __syncthreads();
  for(int off=1; off<256; off<<=1){
    int v=psum[t];
    int add=(t>=off)?psum[t-off]:0;
    __syncthreads();
    psum[t]=v+add;
    __syncthreads();
  }
  int excl=psum[t]-s;
  #pragma unroll
  for(int i=0;i<8;++i){
    if(base+i<n){ rowptr[base+i]=excl; deg[base+i]=excl; }  // deg becomes LDS cursor
    excl+=loc[i];
  }
  if(t==255) rowptr[n]=psum[255];
  __syncthreads();
  for(int e=t;e<E;e+=256){
    int d=eidx[E+e];
    int pos=atomicAdd(&deg[d],1);
    elist[pos]=e;
  }
}

// one launch: [0,11)=w3j, [11,363)=pack_w2, [363,363+hblocks)=h, optional last=csr(+fill)
__global__ __launch_bounds__(256) void prep_kernel(float* w3j,
    const float* __restrict__ W2, _Float16* __restrict__ w2h,
    const float* __restrict__ radial, const float* __restrict__ W1,
    _Float16* __restrict__ h16g, int E, float silu_cst,
    const int* __restrict__ eidx, int* __restrict__ rowptr, int* __restrict__ elist,
    int n_nodes, int hblocks){
  int b=blockIdx.x, t=threadIdx.x;
  if(b<NINS)                  w3j_body(b, t, w3j);
  else if(b<NINS+352)         pack_body(b-NINS, t, W2, w2h);
  else if(b<NINS+352+hblocks) h_body(b-NINS-352, t, radial, W1, h16g, E, silu_cst);
  else                        csr_body(t, eidx, rowptr, elist, E, n_nodes);
}

// ---------------- gather + fused self-connection ----------------
__global__ __launch_bounds__(256) void gather_kernel(const float* __restrict__ msgbuf,
    const int* __restrict__ rowptr, const int* __restrict__ elist,
    const float* __restrict__ x,
    const float* __restrict__ W0, const float* __restrict__ W1s, const float* __restrict__ W2s,
    float* __restrict__ out, int n_nodes)
{
  int n=blockIdx.x;
  if(n>=n_nodes) return;
  int s0=rowptr[n], s1=rowptr[n+1];
  const float inv=0.17677669529663689f;  // 1/sqrt(32)
  for(int o=threadIdx.x; o<IND; o+=blockDim.x){
    float acc=0.f;
    for(int j=s0;j<s1;++j)
      acc += msgbuf[(size_t)elist[j]*IND + o];
    const float* W; int w,k,d,xo;
    if(o<32){W=W0; w=o; k=0; d=1; xo=0;}
    else if(o<128){int r=o-32; W=W1s; d=3; w=r/3; k=r-w*3; xo=32;}
    else {int r=o-128; W=W2s; d=5; w=r/5; k=r-w*5; xo=128;}
    float ssc=0.f;
    const float* xr=x+(size_t)n*IND+xo+k;
    for(int u=0;u<32;++u) ssc += xr[u*d]*W[u*32+w];
    out[(size_t)n*IND+o]=acc + ssc*inv;
  }
}

// ---------------- self connection (fallback path only) ----------------
__global__ __launch_bounds__(256) void sc_kernel(const float* __restrict__ x,
  const float* __restrict__ W0, const float* __restrict__ W1s, const float* __restrict__ W2s,
  float* __restrict__ out, int n_nodes)
{
  int n=blockIdx.x;
  if(n>=n_nodes) return;
  const float inv=0.17677669529663689f;
  for(int o=threadIdx.x; o<IND; o+=blockDim.x){
    const float* W; int w,k,d,xo;
    if(o<32){W=W0; w=o; k=0; d=1; xo=0;}
    else if(o<128){int r=o-32; W=W1s; d=3; w=r/3; k=r-w*3; xo=32;}
    else {int r=o-128; W=W2s; d=5; w=r/5; k=r-w*5; xo=128;}
    float s=0.f;
    const float* xr=x+(size_t)n*IND+xo+k;
    for(int u=0;u<32;++u) s += xr[u*d]*W[u*32+w];
    out[(size_t)n*IND+o]=s*inv;
  }
}

// ---------------- tp building blocks ----------------
template<int INS>
__device__ __forceinline__ void b1_step(const float* __restrict__ w3j,
    const float* __restrict__ sh, float (*shw)[SHWP], int t, int e0, int E)
{
  constexpr int L1v=kL1[INS], L2v=kL2[INS];
  constexpr int D1=2*L1v+1, D2=2*L2v+1, D3=2*kL3[INS]+1;
  constexpr int SO=(L2v==0)?0:(L2v==1?1:4);
  const float* w3=w3j+kW3OFF[INS];
  constexpr int NN=TILE_E*D1*D3;
  for(int idx=t; idx<NN; idx+=256){
    int e=idx/(D1*D3), r=idx-e*(D1*D3);
    int i=r/D3, k=r-i*D3;
    int eg=e0+e;
    float s=0.f;
    if(eg<E){
      #pragma unroll
      for(int j=0;j<D2;++j) s += w3[(i*D2+j)*D3+k]*sh[(size_t)eg*SHD+SO+j];
    }
    shw[e][r]=s;
  }
}

template<int INS>
__device__ __forceinline__ void b2_step(const float* __restrict__ x,
    const int* __restrict__ eidx, const float (*shw)[SHWP], float (*yb)[YROW],
    int t, int e0, int E)
{
  constexpr int L1v=kL1[INS];
  constexpr int D1=2*L1v+1, D3=2*kL3[INS]+1;
  constexpr int XO=(L1v==0)?0:(L1v==1?32:128);
  constexpr int NN=TILE_E*32*D3;
  for(int idx=t; idx<NN; idx+=256){
    int e=idx/(32*D3), r=idx-e*(32*D3);
    int k=r>>5, u=r&31;
    int eg=e0+e;
    float s=0.f;
    if(eg<E){
      int srn=eidx[eg];
      const float* xr=x+(size_t)srn*IND+XO+u*D1;
      #pragma unroll
      for(int i=0;i<D1;++i) s += shw[e][i*D3+k]*xr[i];
    }
    yb[e][k*32+u]=s;
  }
}

// compute phase (r16 form: af loaded per uc, no prefetch)
template<int INS, int ND3>
__device__ __forceinline__ void comp_step(const float (*yb)[YROW],
    const half8* __restrict__ w2p,
    half8 hb0, half8 hb1,
    int ln, int eA, int upb, int wv,
    float (&p0)[4*ND3])
{
  constexpr int D3=2*kL3[INS]+1;
  static_assert(D3==ND3, "group/ins D3 mismatch");

  #pragma unroll 1
  for(int uc=0; uc<4; ++uc){
    const half8* bp = w2p + (size_t)((INS*4+uc)*16 + wv*4)*128 + ln;
    half8 af[8];
    #pragma unroll
    for(int q=0;q<4;++q){ af[2*q]=bp[q*128]; af[2*q+1]=bp[q*128+64]; }

    f32x4 yv0[ND3];
    #pragma unroll
    for(int k=0;k<ND3;++k)
      yv0[k]=*(const f32x4*)&yb[eA][k*32 + uc*8 + upb];

    f32x4 z; z[0]=0.f; z[1]=0.f; z[2]=0.f; z[3]=0.f;
    #pragma unroll
    for(int q=0;q<4;++q){
      f32x4 a0=__builtin_amdgcn_mfma_f32_16x16x32_f16(af[2*q],  hb0,z,0,0,0);
      a0      =__builtin_amdgcn_mfma_f32_16x16x32_f16(af[2*q+1],hb1,a0,0,0,0);
      #pragma unroll
      for(int k=0;k<ND3;++k)
        p0[q*ND3+k] += a0[0]*yv0[k][0]+a0[1]*yv0[k][1]+a0[2]*yv0[k][2]+a0[3]*yv0[k][3];
    }
  }
}

template<int ND3>
__device__ __forceinline__ void flush_set(float* __restrict__ out,
    float* __restrict__ msgbuf, int eg, int d, int E, int OO,
    float pw, int gA, int wsel, int wv, float (&pacc)[4*ND3])
{
  constexpr int KHI=(ND3+1)/2;
  #pragma unroll
  for(int q=0;q<4;++q){
    #pragma unroll
    for(int k=0;k<ND3;++k){
      float p = pacc[q*ND3+k] + __shfl_xor(pacc[q*ND3+k], 16, 64);
      bool mine = (gA&1) ? (k>=KHI) : (k<KHI);
      if(mine && eg<E){
        int w=(wv*4+q)*2+wsel;
        if(msgbuf) msgbuf[(size_t)eg*IND + OO + w*ND3 + k] = pw*p;
        else       atomicAdd(&out[(size_t)d*IND + OO + w*ND3 + k], pw*p);
      }
    }
  }
}

// ---------------- fused MFMA tensor product (r16: dbuf ybuf, 1 barrier/ins, TILE_E=16) ----------------
// grid = 3*ceil(E/16): block bid -> etile=bid/3, l3-group g=bid%3
__global__ __launch_bounds__(256) void tp_kernel(
    const float* __restrict__ x, const int* __restrict__ eidx,
    const float* __restrict__ sh, const _Float16* __restrict__ h16g,
    const _Float16* __restrict__ w2h, const float* __restrict__ w3j,
    float* __restrict__ out, float* __restrict__ msgbuf,
    int E, float pwc0, float pwc1, float pwc2)
{
  __shared__ float shw[2][TILE_E][SHWP];
  __shared__ float ybuf[2][TILE_E][YROW];

  const int t=threadIdx.x;
  const int bid=blockIdx.x;
  const int etile=bid/3, g=bid-etile*3;
  const int e0=etile*TILE_E;

  const int ln=t&63, wv=t>>6;
  const int eA=ln&15, gA=ln>>4;
  const int upb=(gA&1)*4;
  const int wsel=gA>>1;
  const int eg0=e0+eA;

  const int d0 = (eg0<E)? eidx[E+eg0] : -1;

  half8 hb0, hb1;
  #pragma unroll
  for(int i=0;i<8;++i){ hb0[i]=(_Float16)0.f; hb1[i]=(_Float16)0.f; }
  if(eg0<E){
    hb0=*(const half8*)&h16g[(size_t)eg0*64 + gA*8];
    hb1=*(const half8*)&h16g[(size_t)eg0*64 + 32 + gA*8];
  }

  const half8* w2p=(const half8*)w2h;

  if(g==0){
    float p0[4]={};
    b1_step<0>(w3j,sh,shw[0],t,e0,E); __syncthreads();
    b2_step<0>(x,eidx,shw[0],ybuf[0],t,e0,E); b1_step<4>(w3j,sh,shw[1],t,e0,E); __syncthreads();
    comp_step<0,1>(ybuf[0],w2p,hb0,hb1,ln,eA,upb,wv,p0);
    b2_step<4>(x,eidx,shw[1],ybuf[1],t,e0,E); b1_step<9>(w3j,sh,shw[0],t,e0,E); __syncthreads();
    comp_step<4,1>(ybuf[1],w2p,hb0,hb1,ln,eA,upb,wv,p0);
    b2_step<9>(x,eidx,shw[0],ybuf[0],t,e0,E); __syncthreads();
    comp_step<9,1>(ybuf[0],w2p,hb0,hb1,ln,eA,upb,wv,p0);
    flush_set<1>(out,msgbuf,eg0,d0,E,0,pwc0,gA,wsel,wv,p0);
  } else if(g==1){
    float p0[12]={};
    b1_step<1>(w3j,sh,shw[0],t,e0,E); __syncthreads();
    b2_step<1>(x,eidx,shw[0],ybuf[0],t,e0,E); b1_step<3>(w3j,sh,shw[1],t,e0,E); __syncthreads();
    comp_step<1,3>(ybuf[0],w2p,hb0,hb1,ln,eA,upb,wv,p0);
    b2_step<3>(x,eidx,shw[1],ybuf[1],t,e0,E); b1_step<6>(w3j,sh,shw[0],t,e0,E); __syncthreads();
    comp_step<3,3>(ybuf[1],w2p,hb0,hb1,ln,eA,upb,wv,p0);
    b2_step<6>(x,eidx,shw[0],ybuf[0],t,e0,E); b1_step<8>(w3j,sh,shw[1],t,e0,E); __syncthreads();
    comp_step<6,3>(ybuf[0],w2p,hb0,hb1,ln,eA,upb,wv,p0);
    b2_step<8>(x,eidx,shw[1],ybuf[1],t,e0,E); __syncthreads();
    comp_step<8,3>(ybuf[1],w2p,hb0,hb1,ln,eA,upb,wv,p0);
    flush_set<3>(out,msgbuf,eg0,d0,E,32,pwc1,gA,wsel,wv,p0);
  } else {
    float p0[20]={};
    b1_step<2>(w3j,sh,shw[0],t,e0,E); __syncthreads();
    b2_step<2>(x,eidx,shw[0],ybuf[0],t,e0,E); b1_step<5>(w3j,sh,shw[1],t,e0,E); __syncthreads();
    comp_step<2,5>(ybuf[0],w2p,hb0,hb1,ln,eA,upb,wv,p0);
    b2_step<5>(x,eidx,shw[1],ybuf[1],t,e0,E); b1_step<7>(w3j,sh,shw[0],t,e0,E); __syncthreads();
    comp_step<5,5>(ybuf[1],w2p,hb0,hb1,ln,eA,upb,wv,p0);
    b2_step<7>(x,eidx,shw[0],ybuf[0],t,e0,E); b1_step<10>(w3j,sh,shw[1],t,e0,E); __syncthreads();
    comp_step<7,5>(ybuf[0],w2p,hb0,hb1,ln,eA,upb,wv,p0);
    b2_step<10>(x,eidx,shw[1],ybuf[1],t,e0,E); __syncthreads();
    comp_step<10,5>(ybuf[1],w2p,hb0,hb1,ln,eA,upb,wv,p0);
    flush_set<5>(out,msgbuf,eg0,d0,E,128,pwc2,gA,wsel,wv,p0);
  }
}

extern "C" void kernel_launch(void* const* d_in, const int* in_sizes, int n_in,
                              void* d_out, int out_size, void* d_ws, size_t ws_size,
                              hipStream_t stream){
  const float* x     =(const float*)d_in[0];
  const int*   eidx  =(const int*)  d_in[1];
  const float* sh    =(const float*)d_in[2];
  const float* radial=(const float*)d_in[3];
  const float* W1    =(const float*)d_in[4];
  const float* W2    =(const float*)d_in[5];
  const float* Wsc0  =(const float*)d_in[6];
  const float* Wsc1  =(const float*)d_in[7];
  const float* Wsc2  =(const float*)d_in[8];
  float* out=(float*)d_out;
  int n_nodes=in_sizes[0]/IND;
  int E=in_sizes[1]/2;

  float inv10=1.0f/sqrtf(10.0f);
  float pwc0=sqrtf(1.0f/96.0f) *0.125f*inv10;
  float pwc1=sqrtf(3.0f/128.0f)*0.125f*inv10;
  float pwc2=sqrtf(5.0f/128.0f)*0.125f*inv10;
  float silu_cst=1.67682f;

  // workspace layout
  size_t off=0;
  auto alloc=[&](size_t bytes)->size_t{ size_t o=off; off=(off+bytes+255)&~(size_t)255; return o; };
  size_t o_w3j = alloc(2048);
  size_t o_w2h = alloc((size_t)704*2*64*8*2);          // 1.44 MB f16
  size_t o_h16 = alloc((size_t)E*64*2);                // 2.56 MB f16
  size_t o_row = alloc((size_t)(n_nodes+64)*4);
  size_t o_eli = alloc((size_t)E*4);
  size_t o_msg = alloc((size_t)E*IND*4);               // 23 MB
  bool use_msg = (off <= ws_size) && (n_nodes <= 2048);

  char* ws=(char*)d_ws;
  float*     w3j =(float*)(ws+o_w3j);
  _Float16*  w2h =(_Float16*)(ws+o_w2h);
  _Float16*  h16g=(_Float16*)(ws+o_h16);
  int*       row =(int*)(ws+o_row);
  int*       eli =(int*)(ws+o_eli);
  float*     msg =(float*)(ws+o_msg);

  int ntile=(E+TILE_E-1)/TILE_E;
  int hblocks=(E*64+255)/256;
  int prep_blocks = NINS+352+hblocks + (use_msg?1:0);

  hipLaunchKernelGGL(prep_kernel, dim3(prep_blocks), dim3(256), 0, stream,
                     w3j, W2, w2h, radial, W1, h16g, E, silu_cst,
                     eidx, row, eli, n_nodes, hblocks);

  if(use_msg){
    hipLaunchKernelGGL(tp_kernel, dim3(3*ntile), dim3(256), 0, stream,
                       x, eidx, sh, h16g, w2h, w3j, out, msg, E, pwc0, pwc1, pwc2);
    hipLaunchKernelGGL(gather_kernel, dim3(n_nodes), dim3(256), 0, stream,
                       msg, row, eli, x, Wsc0, Wsc1, Wsc2, out, n_nodes);
  } else {
    hipLaunchKernelGGL(sc_kernel, dim3(n_nodes), dim3(256), 0, stream,
                       x, Wsc0, Wsc1, Wsc2, out, n_nodes);
    hipLaunchKernelGGL(tp_kernel, dim3(3*ntile), dim3(256), 0, stream,
                       x, eidx, sh, h16g, w2h, w3j, out, (float*)nullptr, E, pwc0, pwc1, pwc2);
  }
}

// Round 20
// 190.153 us; speedup vs baseline: 2.3839x; 1.1360x over previous
//
#include <hip/hip_runtime.h>
#include <math.h>

#define TILE_E 16
#define NINS 11
#define IND 288
#define SHD 9
#define W2N 11264
#define YROW 164    // ybuf row stride (f32): (164e)%32=4e -> b128 reads 2-way (free)
#define SHWP 28     // shw row pad

typedef _Float16 half8 __attribute__((ext_vector_type(8)));
typedef float f32x4 __attribute__((ext_vector_type(4)));

constexpr int kL1[NINS] = {0,0,0,1,1,1,1,2,2,2,2};
constexpr int kL2[NINS] = {0,1,2,0,1,1,2,0,1,2,2};
constexpr int kL3[NINS] = {0,1,2,1,0,2,1,2,1,0,2};
constexpr int kW3OFF[NINS] = {0,1,10,35,44,53,98,143,168,213,238};

// ---------------- Wigner 3j (exact port of reference) ----------------
__device__ double dfac(int n){ double r=1.0; for(int i=2;i<=n;++i) r*=(double)i; return r; }

__device__ void qmat_dev(int l,double* qr,double* qi){
  int d=2*l+1;
  for(int i=0;i<d*d;++i){qr[i]=0.0;qi[i]=0.0;}
  const double s=0.70710678118654752440;
  for(int m=-l;m<0;++m){
    qr[(l+m)*d+(l-m)]=s;
    qi[(l+m)*d+(l+m)]=-s;
  }
  qr[l*d+l]=1.0;
  for(int m=1;m<=l;++m){
    double sg=(m&1)?-1.0:1.0;
    qr[(l+m)*d+(l+m)]=sg*s;
    qi[(l+m)*d+(l-m)]=sg*s;
  }
  if(l==1){ for(int i=0;i<d*d;++i){ double a=qr[i],b=qi[i]; qr[i]=b; qi[i]=-a; } }
  else if(l==2){ for(int i=0;i<d*d;++i){ qr[i]=-qr[i]; qi[i]=-qi[i]; } }
}

__device__ void w3j_body(int ins, int t, float* w3j){
  const int l1=kL1[ins],l2=kL2[ins],l3=kL3[ins];
  const int d1=2*l1+1,d2=2*l2+1,d3=2*l3+1;
  const int n=d1*d2*d3;

  __shared__ double C[125];
  __shared__ double R[125];
  __shared__ double q1r[25],q1i[25],q2r[25],q2i[25],q3r[25],q3i[25];
  __shared__ double inv;

  for(int i=t;i<125;i+=256) C[i]=0.0;
  if(t==0){
    qmat_dev(l1,q1r,q1i); qmat_dev(l2,q2r,q2i); qmat_dev(l3,q3r,q3i);
  }
  __syncthreads();

  if(t<d1*d2){
    int m1=t/d2-l1, m2=t-(t/d2)*d2-l2;
    int m3=m1+m2;
    if(m3>=-l3 && m3<=l3){
      int vmin=-l1+l2+m3; if(-l1+m1>vmin)vmin=-l1+m1; if(0>vmin)vmin=0;
      int vmax=l2+l3+m1; if(l3-l1+l2<vmax)vmax=l3-l1+l2; if(l3+m3<vmax)vmax=l3+m3;
      double c=sqrt((double)(2*l3+1)*dfac(l3+l1-l2)*dfac(l3-l1+l2)*dfac(l1+l2-l3)
        *dfac(l3+m3)*dfac(l3-m3)
        /(dfac(l1+l2+l3+1)*dfac(l1-m1)*dfac(l1+m1)*dfac(l2-m2)*dfac(l2+m2)));
      double s=0.0;
      for(int v=vmin;v<=vmax;++v){
        double term=dfac(l2+l3+m1-v)*dfac(l1-m1+v)
          /(dfac(v)*dfac(l3-l1+l2-v)*dfac(l3+m3-v)*dfac(v+l1-l2-m3));
        s += (((v+l2+m2)&1)?-1.0:1.0)*term;
      }
      C[((m1+l1)*d2+(m2+l2))*d3+(m3+l3)]=c*s;
    }
  }
  __syncthreads();

  if(t<n){
    int j=t/(d2*d3);
    int rem=t-j*(d2*d3);
    int l=rem/d3, m=rem-l*d3;
    double sr=0.0;
    for(int a=0;a<d1;++a)for(int b=0;b<d2;++b)for(int nn=0;nn<d3;++nn){
      double cv=C[(a*d2+b)*d3+nn];
      if(cv==0.0) continue;
      double xr=q1r[a*d1+j],xi=q1i[a*d1+j];
      double yr=q2r[b*d2+l],yi=q2i[b*d2+l];
      double zr=q3r[nn*d3+m],zi=-q3i[nn*d3+m];
      double pr=xr*yr-xi*yi, pi=xr*yi+xi*yr;
      sr += (pr*zr-pi*zi)*cv;
    }
    R[t]=sr;
  }
  __syncthreads();
  if(t==0){
    double n2=0.0;
    for(int i=0;i<n;++i) n2+=R[i]*R[i];
    inv=1.0/sqrt(n2);
  }
  __syncthreads();
  if(t<n) w3j[kW3OFF[ins]+t]=(float)(R[t]*inv);
}

__device__ void pack_body(int pb, int t, const float* __restrict__ W2,
                          _Float16* __restrict__ w2h){
  int q = pb*256 + t;                        // 704*2*64 = 90112
  if(q >= 704*2*64) return;
  int l = q & 63;
  int s = (q>>6)&1;
  int g = q>>7;
  int ins=g>>6, rem=g&63, uc=rem>>4, tp=rem&15;
  int m = l&15;
  int col = ins*1024 + (uc*8 + (m&7))*32 + tp*2 + (m>>3);
  int c0  = s*32 + ((l>>4)<<3);
  half8 v;
  #pragma unroll
  for(int i=0;i<8;++i) v[i] = (_Float16)W2[(size_t)(c0+i)*W2N + col];
  *(half8*)&w2h[(size_t)q*8] = v;
}

__device__ void h_body(int hb, int t, const float* __restrict__ radial,
    const float* __restrict__ W1, _Float16* __restrict__ h16g, int E, float silu_cst){
  int idx = hb*256 + t;
  int e = idx>>6, c = idx&63;
  if(e>=E) return;
  const float* rr = radial + (size_t)e*64;
  float acc=0.f;
  #pragma unroll 8
  for(int r=0;r<64;++r) acc += rr[r]*W1[r*64+c];
  acc*=0.125f;
  float hv = silu_cst*acc/(1.f+expf(-acc));
  h16g[idx]=(_Float16)hv;
}

// CSR hist + scan in one block (n <= 2048)
__device__ void csr_body(int t, const int* __restrict__ eidx,
    int* __restrict__ rowptr, int* __restrict__ cur, int E, int n){
  __shared__ int deg[2048];
  __shared__ int psum[256];
  for(int i=t;i<2048;i+=256) deg[i]=0;
  __syncthreads();
  for(int e=t;e<E;e+=256) atomicAdd(&deg[eidx[E+e]],1);
  __syncthreads();
  int base=t*8;
  int loc[8]; int s=0;
  #pragma unroll
  for(int i=0;i<8;++i){ loc[i]=(base+i<n)?deg[base+i]:0; s+=loc[i]; }
  psum[t]=s;
  __syncthreads();
  for(int off=1; off<256; off<<=1){
    int v=psum[t];
    int add=(t>=off)?psum[t-off]:0;
    __syncthreads();
    psum[t]=v+add;
    __syncthreads();
  }
  int excl=psum[t]-s;
  #pragma unroll
  for(int i=0;i<8;++i){
    if(base+i<n){ rowptr[base+i]=excl; cur[base+i]=excl; }
    excl+=loc[i];
  }
  if(t==255) rowptr[n]=psum[255];
}

// one launch: block 0 = csr (if enabled, runs first to overlap), then w3j, pack, h
__global__ __launch_bounds__(256) void prep_kernel(float* w3j,
    const float* __restrict__ W2, _Float16* __restrict__ w2h,
    const float* __restrict__ radial, const float* __restrict__ W1,
    _Float16* __restrict__ h16g, int E, float silu_cst,
    const int* __restrict__ eidx, int* __restrict__ rowptr, int* __restrict__ cur,
    int n_nodes, int use_csr){
  int b=blockIdx.x, t=threadIdx.x;
  if(use_csr){
    if(b==0){ csr_body(t, eidx, rowptr, cur, E, n_nodes); return; }
    b-=1;
  }
  if(b<NINS)           w3j_body(b, t, w3j);
  else if(b<NINS+352)  pack_body(b-NINS, t, W2, w2h);
  else                 h_body(b-NINS-352, t, radial, W1, h16g, E, silu_cst);
}

__global__ __launch_bounds__(256) void fill_kernel(const int* __restrict__ eidx,
    int* __restrict__ cursor, int* __restrict__ elist, int E){
  int e=blockIdx.x*256+threadIdx.x;
  if(e>=E) return;
  int d=eidx[E+e];
  int pos=atomicAdd(&cursor[d],1);
  elist[pos]=e;
}

// ---------------- gather + fused self-connection ----------------
__global__ __launch_bounds__(256) void gather_kernel(const float* __restrict__ msgbuf,
    const int* __restrict__ rowptr, const int* __restrict__ elist,
    const float* __restrict__ x,
    const float* __restrict__ W0, const float* __restrict__ W1s, const float* __restrict__ W2s,
    float* __restrict__ out, int n_nodes)
{
  int n=blockIdx.x;
  if(n>=n_nodes) return;
  int s0=rowptr[n], s1=rowptr[n+1];
  const float inv=0.17677669529663689f;  // 1/sqrt(32)
  for(int o=threadIdx.x; o<IND; o+=blockDim.x){
    float acc=0.f;
    for(int j=s0;j<s1;++j)
      acc += msgbuf[(size_t)elist[j]*IND + o];
    const float* W; int w,k,d,xo;
    if(o<32){W=W0; w=o; k=0; d=1; xo=0;}
    else if(o<128){int r=o-32; W=W1s; d=3; w=r/3; k=r-w*3; xo=32;}
    else {int r=o-128; W=W2s; d=5; w=r/5; k=r-w*5; xo=128;}
    float ssc=0.f;
    const float* xr=x+(size_t)n*IND+xo+k;
    for(int u=0;u<32;++u) ssc += xr[u*d]*W[u*32+w];
    out[(size_t)n*IND+o]=acc + ssc*inv;
  }
}

// ---------------- self connection (fallback path only) ----------------
__global__ __launch_bounds__(256) void sc_kernel(const float* __restrict__ x,
  const float* __restrict__ W0, const float* __restrict__ W1s, const float* __restrict__ W2s,
  float* __restrict__ out, int n_nodes)
{
  int n=blockIdx.x;
  if(n>=n_nodes) return;
  const float inv=0.17677669529663689f;
  for(int o=threadIdx.x; o<IND; o+=blockDim.x){
    const float* W; int w,k,d,xo;
    if(o<32){W=W0; w=o; k=0; d=1; xo=0;}
    else if(o<128){int r=o-32; W=W1s; d=3; w=r/3; k=r-w*3; xo=32;}
    else {int r=o-128; W=W2s; d=5; w=r/5; k=r-w*5; xo=128;}
    float s=0.f;
    const float* xr=x+(size_t)n*IND+xo+k;
    for(int u=0;u<32;++u) s += xr[u*d]*W[u*32+w];
    out[(size_t)n*IND+o]=s*inv;
  }
}

// ---------------- tp building blocks ----------------
template<int INS>
__device__ __forceinline__ void b1_step(const float* __restrict__ w3j,
    const float* __restrict__ sh, float (*shw)[SHWP], int t, int e0, int E)
{
  constexpr int L1v=kL1[INS], L2v=kL2[INS];
  constexpr int D1=2*L1v+1, D2=2*L2v+1, D3=2*kL3[INS]+1;
  constexpr int SO=(L2v==0)?0:(L2v==1?1:4);
  const float* w3=w3j+kW3OFF[INS];
  constexpr int NN=TILE_E*D1*D3;
  for(int idx=t; idx<NN; idx+=256){
    int e=idx/(D1*D3), r=idx-e*(D1*D3);
    int i=r/D3, k=r-i*D3;
    int eg=e0+e;
    float s=0.f;
    if(eg<E){
      #pragma unroll
      for(int j=0;j<D2;++j) s += w3[(i*D2+j)*D3+k]*sh[(size_t)eg*SHD+SO+j];
    }
    shw[e][r]=s;
  }
}

template<int INS>
__device__ __forceinline__ void b2_step(const float* __restrict__ x,
    const int* __restrict__ eidx, const float (*shw)[SHWP], float (*yb)[YROW],
    int t, int e0, int E)
{
  constexpr int L1v=kL1[INS];
  constexpr int D1=2*L1v+1, D3=2*kL3[INS]+1;
  constexpr int XO=(L1v==0)?0:(L1v==1?32:128);
  constexpr int NN=TILE_E*32*D3;
  for(int idx=t; idx<NN; idx+=256){
    int e=idx/(32*D3), r=idx-e*(32*D3);
    int k=r>>5, u=r&31;
    int eg=e0+e;
    float s=0.f;
    if(eg<E){
      int srn=eidx[eg];
      const float* xr=x+(size_t)srn*IND+XO+u*D1;
      #pragma unroll
      for(int i=0;i<D1;++i) s += shw[e][i*D3+k]*xr[i];
    }
    yb[e][k*32+u]=s;
  }
}

// compute phase (r16 form: af loaded per uc, no prefetch)
template<int INS, int ND3>
__device__ __forceinline__ void comp_step(const float (*yb)[YROW],
    const half8* __restrict__ w2p,
    half8 hb0, half8 hb1,
    int ln, int eA, int upb, int wv,
    float (&p0)[4*ND3])
{
  constexpr int D3=2*kL3[INS]+1;
  static_assert(D3==ND3, "group/ins D3 mismatch");

  #pragma unroll 1
  for(int uc=0; uc<4; ++uc){
    const half8* bp = w2p + (size_t)((INS*4+uc)*16 + wv*4)*128 + ln;
    half8 af[8];
    #pragma unroll
    for(int q=0;q<4;++q){ af[2*q]=bp[q*128]; af[2*q+1]=bp[q*128+64]; }

    f32x4 yv0[ND3];
    #pragma unroll
    for(int k=0;k<ND3;++k)
      yv0[k]=*(const f32x4*)&yb[eA][k*32 + uc*8 + upb];

    f32x4 z; z[0]=0.f; z[1]=0.f; z[2]=0.f; z[3]=0.f;
    #pragma unroll
    for(int q=0;q<4;++q){
      f32x4 a0=__builtin_amdgcn_mfma_f32_16x16x32_f16(af[2*q],  hb0,z,0,0,0);
      a0      =__builtin_amdgcn_mfma_f32_16x16x32_f16(af[2*q+1],hb1,a0,0,0,0);
      #pragma unroll
      for(int k=0;k<ND3;++k)
        p0[q*ND3+k] += a0[0]*yv0[k][0]+a0[1]*yv0[k][1]+a0[2]*yv0[k][2]+a0[3]*yv0[k][3];
    }
  }
}

template<int ND3>
__device__ __forceinline__ void flush_set(float* __restrict__ out,
    float* __restrict__ msgbuf, int eg, int d, int E, int OO,
    float pw, int gA, int wsel, int wv, float (&pacc)[4*ND3])
{
  constexpr int KHI=(ND3+1)/2;
  #pragma unroll
  for(int q=0;q<4;++q){
    #pragma unroll
    for(int k=0;k<ND3;++k){
      float p = pacc[q*ND3+k] + __shfl_xor(pacc[q*ND3+k], 16, 64);
      bool mine = (gA&1) ? (k>=KHI) : (k<KHI);
      if(mine && eg<E){
        int w=(wv*4+q)*2+wsel;
        if(msgbuf) msgbuf[(size_t)eg*IND + OO + w*ND3 + k] = pw*p;
        else       atomicAdd(&out[(size_t)d*IND + OO + w*ND3 + k], pw*p);
      }
    }
  }
}

// ---------------- fused MFMA tensor product (r16: dbuf ybuf, 1 barrier/ins, TILE_E=16) ----------------
// grid = 3*ceil(E/16): block bid -> etile=bid/3, l3-group g=bid%3
__global__ __launch_bounds__(256) void tp_kernel(
    const float* __restrict__ x, const int* __restrict__ eidx,
    const float* __restrict__ sh, const _Float16* __restrict__ h16g,
    const _Float16* __restrict__ w2h, const float* __restrict__ w3j,
    float* __restrict__ out, float* __restrict__ msgbuf,
    int E, float pwc0, float pwc1, float pwc2)
{
  __shared__ float shw[2][TILE_E][SHWP];
  __shared__ float ybuf[2][TILE_E][YROW];

  const int t=threadIdx.x;
  const int bid=blockIdx.x;
  const int etile=bid/3, g=bid-etile*3;
  const int e0=etile*TILE_E;

  const int ln=t&63, wv=t>>6;
  const int eA=ln&15, gA=ln>>4;
  const int upb=(gA&1)*4;
  const int wsel=gA>>1;
  const int eg0=e0+eA;

  const int d0 = (eg0<E)? eidx[E+eg0] : -1;

  half8 hb0, hb1;
  #pragma unroll
  for(int i=0;i<8;++i){ hb0[i]=(_Float16)0.f; hb1[i]=(_Float16)0.f; }
  if(eg0<E){
    hb0=*(const half8*)&h16g[(size_t)eg0*64 + gA*8];
    hb1=*(const half8*)&h16g[(size_t)eg0*64 + 32 + gA*8];
  }

  const half8* w2p=(const half8*)w2h;

  if(g==0){
    float p0[4]={};
    b1_step<0>(w3j,sh,shw[0],t,e0,E); __syncthreads();
    b2_step<0>(x,eidx,shw[0],ybuf[0],t,e0,E); b1_step<4>(w3j,sh,shw[1],t,e0,E); __syncthreads();
    comp_step<0,1>(ybuf[0],w2p,hb0,hb1,ln,eA,upb,wv,p0);
    b2_step<4>(x,eidx,shw[1],ybuf[1],t,e0,E); b1_step<9>(w3j,sh,shw[0],t,e0,E); __syncthreads();
    comp_step<4,1>(ybuf[1],w2p,hb0,hb1,ln,eA,upb,wv,p0);
    b2_step<9>(x,eidx,shw[0],ybuf[0],t,e0,E); __syncthreads();
    comp_step<9,1>(ybuf[0],w2p,hb0,hb1,ln,eA,upb,wv,p0);
    flush_set<1>(out,msgbuf,eg0,d0,E,0,pwc0,gA,wsel,wv,p0);
  } else if(g==1){
    float p0[12]={};
    b1_step<1>(w3j,sh,shw[0],t,e0,E); __syncthreads();
    b2_step<1>(x,eidx,shw[0],ybuf[0],t,e0,E); b1_step<3>(w3j,sh,shw[1],t,e0,E); __syncthreads();
    comp_step<1,3>(ybuf[0],w2p,hb0,hb1,ln,eA,upb,wv,p0);
    b2_step<3>(x,eidx,shw[1],ybuf[1],t,e0,E); b1_step<6>(w3j,sh,shw[0],t,e0,E); __syncthreads();
    comp_step<3,3>(ybuf[1],w2p,hb0,hb1,ln,eA,upb,wv,p0);
    b2_step<6>(x,eidx,shw[0],ybuf[0],t,e0,E); b1_step<8>(w3j,sh,shw[1],t,e0,E); __syncthreads();
    comp_step<6,3>(ybuf[0],w2p,hb0,hb1,ln,eA,upb,wv,p0);
    b2_step<8>(x,eidx,shw[1],ybuf[1],t,e0,E); __syncthreads();
    comp_step<8,3>(ybuf[1],w2p,hb0,hb1,ln,eA,upb,wv,p0);
    flush_set<3>(out,msgbuf,eg0,d0,E,32,pwc1,gA,wsel,wv,p0);
  } else {
    float p0[20]={};
    b1_step<2>(w3j,sh,shw[0],t,e0,E); __syncthreads();
    b2_step<2>(x,eidx,shw[0],ybuf[0],t,e0,E); b1_step<5>(w3j,sh,shw[1],t,e0,E); __syncthreads();
    comp_step<2,5>(ybuf[0],w2p,hb0,hb1,ln,eA,upb,wv,p0);
    b2_step<5>(x,eidx,shw[1],ybuf[1],t,e0,E); b1_step<7>(w3j,sh,shw[0],t,e0,E); __syncthreads();
    comp_step<5,5>(ybuf[1],w2p,hb0,hb1,ln,eA,upb,wv,p0);
    b2_step<7>(x,eidx,shw[0],ybuf[0],t,e0,E); b1_step<10>(w3j,sh,shw[1],t,e0,E); __syncthreads();
    comp_step<7,5>(ybuf[0],w2p,hb0,hb1,ln,eA,upb,wv,p0);
    b2_step<10>(x,eidx,shw[1],ybuf[1],t,e0,E); __syncthreads();
    comp_step<10,5>(ybuf[1],w2p,hb0,hb1,ln,eA,upb,wv,p0);
    flush_set<5>(out,msgbuf,eg0,d0,E,128,pwc2,gA,wsel,wv,p0);
  }
}

extern "C" void kernel_launch(void* const* d_in, const int* in_sizes, int n_in,
                              void* d_out, int out_size, void* d_ws, size_t ws_size,
                              hipStream_t stream){
  const float* x     =(const float*)d_in[0];
  const int*   eidx  =(const int*)  d_in[1];
  const float* sh    =(const float*)d_in[2];
  const float* radial=(const float*)d_in[3];
  const float* W1    =(const float*)d_in[4];
  const float* W2    =(const float*)d_in[5];
  const float* Wsc0  =(const float*)d_in[6];
  const float* Wsc1  =(const float*)d_in[7];
  const float* Wsc2  =(const float*)d_in[8];
  float* out=(float*)d_out;
  int n_nodes=in_sizes[0]/IND;
  int E=in_sizes[1]/2;

  float inv10=1.0f/sqrtf(10.0f);
  float pwc0=sqrtf(1.0f/96.0f) *0.125f*inv10;
  float pwc1=sqrtf(3.0f/128.0f)*0.125f*inv10;
  float pwc2=sqrtf(5.0f/128.0f)*0.125f*inv10;
  float silu_cst=1.67682f;

  // workspace layout
  size_t off=0;
  auto alloc=[&](size_t bytes)->size_t{ size_t o=off; off=(off+bytes+255)&~(size_t)255; return o; };
  size_t o_w3j = alloc(2048);
  size_t o_w2h = alloc((size_t)704*2*64*8*2);          // 1.44 MB f16
  size_t o_h16 = alloc((size_t)E*64*2);                // 2.56 MB f16
  size_t o_row = alloc((size_t)(n_nodes+64)*4);
  size_t o_cur = alloc((size_t)(n_nodes+64)*4);
  size_t o_eli = alloc((size_t)E*4);
  size_t o_msg = alloc((size_t)E*IND*4);               // 23 MB
  bool use_msg = (off <= ws_size) && (n_nodes <= 2048);

  char* ws=(char*)d_ws;
  float*     w3j =(float*)(ws+o_w3j);
  _Float16*  w2h =(_Float16*)(ws+o_w2h);
  _Float16*  h16g=(_Float16*)(ws+o_h16);
  int*       row =(int*)(ws+o_row);
  int*       cur =(int*)(ws+o_cur);
  int*       eli =(int*)(ws+o_eli);
  float*     msg =(float*)(ws+o_msg);

  int ntile=(E+TILE_E-1)/TILE_E;
  int hblocks=(E*64+255)/256;
  int prep_blocks = NINS+352+hblocks + (use_msg?1:0);

  hipLaunchKernelGGL(prep_kernel, dim3(prep_blocks), dim3(256), 0, stream,
                     w3j, W2, w2h, radial, W1, h16g, E, silu_cst,
                     eidx, row, cur, n_nodes, use_msg?1:0);

  if(use_msg){
    hipLaunchKernelGGL(fill_kernel, dim3((E+255)/256), dim3(256), 0, stream, eidx, cur, eli, E);
    hipLaunchKernelGGL(tp_kernel, dim3(3*ntile), dim3(256), 0, stream,
                       x, eidx, sh, h16g, w2h, w3j, out, msg, E, pwc0, pwc1, pwc2);
    hipLaunchKernelGGL(gather_kernel, dim3(n_nodes), dim3(256), 0, stream,
                       msg, row, eli, x, Wsc0, Wsc1, Wsc2, out, n_nodes);
  } else {
    hipLaunchKernelGGL(sc_kernel, dim3(n_nodes), dim3(256), 0, stream,
                       x, Wsc0, Wsc1, Wsc2, out, n_nodes);
    hipLaunchKernelGGL(tp_kernel, dim3(3*ntile), dim3(256), 0, stream,
                       x, eidx, sh, h16g, w2h, w3j, out, (float*)nullptr, E, pwc0, pwc1, pwc2);
  }
}

// Round 21
// 184.215 us; speedup vs baseline: 2.4608x; 1.0322x over previous
//
#include <hip/hip_runtime.h>
#include <math.h>

#define TILE_E 16
#define NINS 11
#define IND 288
#define SHD 9
#define W2N 11264
#define YROW 164    // ybuf row stride (f32): (164e)%32=4e -> b128 reads 2-way (free)
#define SHWP 28     // shw row pad

typedef _Float16 half8 __attribute__((ext_vector_type(8)));
typedef float f32x4 __attribute__((ext_vector_type(4)));

constexpr int kL1[NINS] = {0,0,0,1,1,1,1,2,2,2,2};
constexpr int kL2[NINS] = {0,1,2,0,1,1,2,0,1,2,2};
constexpr int kL3[NINS] = {0,1,2,1,0,2,1,2,1,0,2};
constexpr int kW3OFF[NINS] = {0,1,10,35,44,53,98,143,168,213,238};

// ---------------- Wigner 3j (exact port of reference) ----------------
__device__ double dfac(int n){ double r=1.0; for(int i=2;i<=n;++i) r*=(double)i; return r; }

__device__ void qmat_dev(int l,double* qr,double* qi){
  int d=2*l+1;
  for(int i=0;i<d*d;++i){qr[i]=0.0;qi[i]=0.0;}
  const double s=0.70710678118654752440;
  for(int m=-l;m<0;++m){
    qr[(l+m)*d+(l-m)]=s;
    qi[(l+m)*d+(l+m)]=-s;
  }
  qr[l*d+l]=1.0;
  for(int m=1;m<=l;++m){
    double sg=(m&1)?-1.0:1.0;
    qr[(l+m)*d+(l+m)]=sg*s;
    qi[(l+m)*d+(l-m)]=sg*s;
  }
  if(l==1){ for(int i=0;i<d*d;++i){ double a=qr[i],b=qi[i]; qr[i]=b; qi[i]=-a; } }
  else if(l==2){ for(int i=0;i<d*d;++i){ qr[i]=-qr[i]; qi[i]=-qi[i]; } }
}

__device__ void w3j_body(int ins, int t, float* w3j){
  const int l1=kL1[ins],l2=kL2[ins],l3=kL3[ins];
  const int d1=2*l1+1,d2=2*l2+1,d3=2*l3+1;
  const int n=d1*d2*d3;

  __shared__ double C[125];
  __shared__ double R[125];
  __shared__ double q1r[25],q1i[25],q2r[25],q2i[25],q3r[25],q3i[25];
  __shared__ double inv;

  for(int i=t;i<125;i+=256) C[i]=0.0;
  if(t==0){
    qmat_dev(l1,q1r,q1i); qmat_dev(l2,q2r,q2i); qmat_dev(l3,q3r,q3i);
  }
  __syncthreads();

  if(t<d1*d2){
    int m1=t/d2-l1, m2=t-(t/d2)*d2-l2;
    int m3=m1+m2;
    if(m3>=-l3 && m3<=l3){
      int vmin=-l1+l2+m3; if(-l1+m1>vmin)vmin=-l1+m1; if(0>vmin)vmin=0;
      int vmax=l2+l3+m1; if(l3-l1+l2<vmax)vmax=l3-l1+l2; if(l3+m3<vmax)vmax=l3+m3;
      double c=sqrt((double)(2*l3+1)*dfac(l3+l1-l2)*dfac(l3-l1+l2)*dfac(l1+l2-l3)
        *dfac(l3+m3)*dfac(l3-m3)
        /(dfac(l1+l2+l3+1)*dfac(l1-m1)*dfac(l1+m1)*dfac(l2-m2)*dfac(l2+m2)));
      double s=0.0;
      for(int v=vmin;v<=vmax;++v){
        double term=dfac(l2+l3+m1-v)*dfac(l1-m1+v)
          /(dfac(v)*dfac(l3-l1+l2-v)*dfac(l3+m3-v)*dfac(v+l1-l2-m3));
        s += (((v+l2+m2)&1)?-1.0:1.0)*term;
      }
      C[((m1+l1)*d2+(m2+l2))*d3+(m3+l3)]=c*s;
    }
  }
  __syncthreads();

  if(t<n){
    int j=t/(d2*d3);
    int rem=t-j*(d2*d3);
    int l=rem/d3, m=rem-l*d3;
    double sr=0.0;
    for(int a=0;a<d1;++a)for(int b=0;b<d2;++b)for(int nn=0;nn<d3;++nn){
      double cv=C[(a*d2+b)*d3+nn];
      if(cv==0.0) continue;
      double xr=q1r[a*d1+j],xi=q1i[a*d1+j];
      double yr=q2r[b*d2+l],yi=q2i[b*d2+l];
      double zr=q3r[nn*d3+m],zi=-q3i[nn*d3+m];
      double pr=xr*yr-xi*yi, pi=xr*yi+xi*yr;
      sr += (pr*zr-pi*zi)*cv;
    }
    R[t]=sr;
  }
  __syncthreads();
  if(t==0){
    double n2=0.0;
    for(int i=0;i<n;++i) n2+=R[i]*R[i];
    inv=1.0/sqrt(n2);
  }
  __syncthreads();
  if(t<n) w3j[kW3OFF[ins]+t]=(float)(R[t]*inv);
}

// pack via LDS staging: block = (ins,uc) covers contiguous 64x256 W2 sub-block.
// col = ins*1024 + u*32 + w with u=uc*8+(m&7), w=tp*2+(m>>3):
//   colbase = ins*1024 + uc*256 ; lcol = (m&7)*32 + tp*2 + (m>>3)
__device__ void pack_body(int blk, int t, const float* __restrict__ W2,
                          _Float16* __restrict__ w2h){
  __shared__ _Float16 tile[64][260];   // 64 rows x 256 cols (+pad), f16
  int ins=blk>>2, uc=blk&3;
  int colbase = ins*1024 + uc*256;
  // coalesced load: consecutive lanes read consecutive cols of one row
  for(int idx=t; idx<64*256; idx+=256){
    int r=idx>>8, c=idx&255;
    tile[r][c]=(_Float16)W2[(size_t)r*W2N + colbase + c];
  }
  __syncthreads();
  // emit fragments: q = (tp,s,l); w2h[((g*2+s)*64+l)*8+i], g=(ins*4+uc)*16+tp
  for(int q=t; q<16*2*64; q+=256){
    int l=q&63, s=(q>>6)&1, tp=q>>7;
    int m=l&15;
    int lcol=(m&7)*32 + tp*2 + (m>>3);
    int c0=s*32 + ((l>>4)<<3);
    int g=(ins*4+uc)*16 + tp;
    half8 v;
    #pragma unroll
    for(int i=0;i<8;++i) v[i]=tile[c0+i][lcol];
    *(half8*)&w2h[((size_t)(g*2+s)*64 + l)*8]=v;
  }
}

__device__ void h_body(int hb, int t, const float* __restrict__ radial,
    const float* __restrict__ W1, _Float16* __restrict__ h16g, int E, float silu_cst){
  int idx = hb*256 + t;
  int e = idx>>6, c = idx&63;
  if(e>=E) return;
  const float* rr = radial + (size_t)e*64;
  float acc=0.f;
  #pragma unroll 8
  for(int r=0;r<64;++r) acc += rr[r]*W1[r*64+c];
  acc*=0.125f;
  float hv = silu_cst*acc/(1.f+expf(-acc));
  h16g[idx]=(_Float16)hv;
}

// CSR hist + scan in one block (n <= 2048)
__device__ void csr_body(int t, const int* __restrict__ eidx,
    int* __restrict__ rowptr, int* __restrict__ cur, int E, int n){
  __shared__ int deg[2048];
  __shared__ int psum[256];
  for(int i=t;i<2048;i+=256) deg[i]=0;
  __syncthreads();
  for(int e=t;e<E;e+=256) atomicAdd(&deg[eidx[E+e]],1);
  __syncthreads();
  int base=t*8;
  int loc[8]; int s=0;
  #pragma unroll
  for(int i=0;i<8;++i){ loc[i]=(base+i<n)?deg[base+i]:0; s+=loc[i]; }
  psum[t]=s;
  __syncthreads();
  for(int off=1; off<256; off<<=1){
    int v=psum[t];
    int add=(t>=off)?psum[t-off]:0;
    __syncthreads();
    psum[t]=v+add;
    __syncthreads();
  }
  int excl=psum[t]-s;
  #pragma unroll
  for(int i=0;i<8;++i){
    if(base+i<n){ rowptr[base+i]=excl; cur[base+i]=excl; }
    excl+=loc[i];
  }
  if(t==255) rowptr[n]=psum[255];
}

// one launch: block 0 = csr (if enabled), then w3j [1,12), pack [12,56), h rest
__global__ __launch_bounds__(256) void prep_kernel(float* w3j,
    const float* __restrict__ W2, _Float16* __restrict__ w2h,
    const float* __restrict__ radial, const float* __restrict__ W1,
    _Float16* __restrict__ h16g, int E, float silu_cst,
    const int* __restrict__ eidx, int* __restrict__ rowptr, int* __restrict__ cur,
    int n_nodes, int use_csr){
  int b=blockIdx.x, t=threadIdx.x;
  if(use_csr){
    if(b==0){ csr_body(t, eidx, rowptr, cur, E, n_nodes); return; }
    b-=1;
  }
  if(b<NINS)          w3j_body(b, t, w3j);
  else if(b<NINS+44)  pack_body(b-NINS, t, W2, w2h);
  else                h_body(b-NINS-44, t, radial, W1, h16g, E, silu_cst);
}

__global__ __launch_bounds__(256) void fill_kernel(const int* __restrict__ eidx,
    int* __restrict__ cursor, int* __restrict__ elist, int E){
  int e=blockIdx.x*256+threadIdx.x;
  if(e>=E) return;
  int d=eidx[E+e];
  int pos=atomicAdd(&cursor[d],1);
  elist[pos]=e;
}

// ---------------- gather + fused self-connection ----------------
__global__ __launch_bounds__(256) void gather_kernel(const float* __restrict__ msgbuf,
    const int* __restrict__ rowptr, const int* __restrict__ elist,
    const float* __restrict__ x,
    const float* __restrict__ W0, const float* __restrict__ W1s, const float* __restrict__ W2s,
    float* __restrict__ out, int n_nodes)
{
  int n=blockIdx.x;
  if(n>=n_nodes) return;
  int s0=rowptr[n], s1=rowptr[n+1];
  const float inv=0.17677669529663689f;  // 1/sqrt(32)
  for(int o=threadIdx.x; o<IND; o+=blockDim.x){
    float acc=0.f;
    for(int j=s0;j<s1;++j)
      acc += msgbuf[(size_t)elist[j]*IND + o];
    const float* W; int w,k,d,xo;
    if(o<32){W=W0; w=o; k=0; d=1; xo=0;}
    else if(o<128){int r=o-32; W=W1s; d=3; w=r/3; k=r-w*3; xo=32;}
    else {int r=o-128; W=W2s; d=5; w=r/5; k=r-w*5; xo=128;}
    float ssc=0.f;
    const float* xr=x+(size_t)n*IND+xo+k;
    for(int u=0;u<32;++u) ssc += xr[u*d]*W[u*32+w];
    out[(size_t)n*IND+o]=acc + ssc*inv;
  }
}

// ---------------- self connection (fallback path only) ----------------
__global__ __launch_bounds__(256) void sc_kernel(const float* __restrict__ x,
  const float* __restrict__ W0, const float* __restrict__ W1s, const float* __restrict__ W2s,
  float* __restrict__ out, int n_nodes)
{
  int n=blockIdx.x;
  if(n>=n_nodes) return;
  const float inv=0.17677669529663689f;
  for(int o=threadIdx.x; o<IND; o+=blockDim.x){
    const float* W; int w,k,d,xo;
    if(o<32){W=W0; w=o; k=0; d=1; xo=0;}
    else if(o<128){int r=o-32; W=W1s; d=3; w=r/3; k=r-w*3; xo=32;}
    else {int r=o-128; W=W2s; d=5; w=r/5; k=r-w*5; xo=128;}
    float s=0.f;
    const float* xr=x+(size_t)n*IND+xo+k;
    for(int u=0;u<32;++u) s += xr[u*d]*W[u*32+w];
    out[(size_t)n*IND+o]=s*inv;
  }
}

// ---------------- tp building blocks ----------------
template<int INS>
__device__ __forceinline__ void b1_step(const float* __restrict__ w3j,
    const float* __restrict__ sh, float (*shw)[SHWP], int t, int e0, int E)
{
  constexpr int L1v=kL1[INS], L2v=kL2[INS];
  constexpr int D1=2*L1v+1, D2=2*L2v+1, D3=2*kL3[INS]+1;
  constexpr int SO=(L2v==0)?0:(L2v==1?1:4);
  const float* w3=w3j+kW3OFF[INS];
  constexpr int NN=TILE_E*D1*D3;
  for(int idx=t; idx<NN; idx+=256){
    int e=idx/(D1*D3), r=idx-e*(D1*D3);
    int i=r/D3, k=r-i*D3;
    int eg=e0+e;
    float s=0.f;
    if(eg<E){
      #pragma unroll
      for(int j=0;j<D2;++j) s += w3[(i*D2+j)*D3+k]*sh[(size_t)eg*SHD+SO+j];
    }
    shw[e][r]=s;
  }
}

template<int INS>
__device__ __forceinline__ void b2_step(const float* __restrict__ x,
    const int* __restrict__ eidx, const float (*shw)[SHWP], float (*yb)[YROW],
    int t, int e0, int E)
{
  constexpr int L1v=kL1[INS];
  constexpr int D1=2*L1v+1, D3=2*kL3[INS]+1;
  constexpr int XO=(L1v==0)?0:(L1v==1?32:128);
  constexpr int NN=TILE_E*32*D3;
  for(int idx=t; idx<NN; idx+=256){
    int e=idx/(32*D3), r=idx-e*(32*D3);
    int k=r>>5, u=r&31;
    int eg=e0+e;
    float s=0.f;
    if(eg<E){
      int srn=eidx[eg];
      const float* xr=x+(size_t)srn*IND+XO+u*D1;
      #pragma unroll
      for(int i=0;i<D1;++i) s += shw[e][i*D3+k]*xr[i];
    }
    yb[e][k*32+u]=s;
  }
}

// compute phase (r16 form: af loaded per uc, no prefetch)
template<int INS, int ND3>
__device__ __forceinline__ void comp_step(const float (*yb)[YROW],
    const half8* __restrict__ w2p,
    half8 hb0, half8 hb1,
    int ln, int eA, int upb, int wv,
    float (&p0)[4*ND3])
{
  constexpr int D3=2*kL3[INS]+1;
  static_assert(D3==ND3, "group/ins D3 mismatch");

  #pragma unroll 1
  for(int uc=0; uc<4; ++uc){
    const half8* bp = w2p + (size_t)((INS*4+uc)*16 + wv*4)*128 + ln;
    half8 af[8];
    #pragma unroll
    for(int q=0;q<4;++q){ af[2*q]=bp[q*128]; af[2*q+1]=bp[q*128+64]; }

    f32x4 yv0[ND3];
    #pragma unroll
    for(int k=0;k<ND3;++k)
      yv0[k]=*(const f32x4*)&yb[eA][k*32 + uc*8 + upb];

    f32x4 z; z[0]=0.f; z[1]=0.f; z[2]=0.f; z[3]=0.f;
    #pragma unroll
    for(int q=0;q<4;++q){
      f32x4 a0=__builtin_amdgcn_mfma_f32_16x16x32_f16(af[2*q],  hb0,z,0,0,0);
      a0      =__builtin_amdgcn_mfma_f32_16x16x32_f16(af[2*q+1],hb1,a0,0,0,0);
      #pragma unroll
      for(int k=0;k<ND3;++k)
        p0[q*ND3+k] += a0[0]*yv0[k][0]+a0[1]*yv0[k][1]+a0[2]*yv0[k][2]+a0[3]*yv0[k][3];
    }
  }
}

template<int ND3>
__device__ __forceinline__ void flush_set(float* __restrict__ out,
    float* __restrict__ msgbuf, int eg, int d, int E, int OO,
    float pw, int gA, int wsel, int wv, float (&pacc)[4*ND3])
{
  constexpr int KHI=(ND3+1)/2;
  #pragma unroll
  for(int q=0;q<4;++q){
    #pragma unroll
    for(int k=0;k<ND3;++k){
      float p = pacc[q*ND3+k] + __shfl_xor(pacc[q*ND3+k], 16, 64);
      bool mine = (gA&1) ? (k>=KHI) : (k<KHI);
      if(mine && eg<E){
        int w=(wv*4+q)*2+wsel;
        if(msgbuf) msgbuf[(size_t)eg*IND + OO + w*ND3 + k] = pw*p;
        else       atomicAdd(&out[(size_t)d*IND + OO + w*ND3 + k], pw*p);
      }
    }
  }
}

// ---------------- fused MFMA tensor product (r16: dbuf ybuf, 1 barrier/ins, TILE_E=16) ----------------
// grid = 3*ceil(E/16): block bid -> etile=bid/3, l3-group g=bid%3
__global__ __launch_bounds__(256) void tp_kernel(
    const float* __restrict__ x, const int* __restrict__ eidx,
    const float* __restrict__ sh, const _Float16* __restrict__ h16g,
    const _Float16* __restrict__ w2h, const float* __restrict__ w3j,
    float* __restrict__ out, float* __restrict__ msgbuf,
    int E, float pwc0, float pwc1, float pwc2)
{
  __shared__ float shw[2][TILE_E][SHWP];
  __shared__ float ybuf[2][TILE_E][YROW];

  const int t=threadIdx.x;
  const int bid=blockIdx.x;
  const int etile=bid/3, g=bid-etile*3;
  const int e0=etile*TILE_E;

  const int ln=t&63, wv=t>>6;
  const int eA=ln&15, gA=ln>>4;
  const int upb=(gA&1)*4;
  const int wsel=gA>>1;
  const int eg0=e0+eA;

  const int d0 = (eg0<E)? eidx[E+eg0] : -1;

  half8 hb0, hb1;
  #pragma unroll
  for(int i=0;i<8;++i){ hb0[i]=(_Float16)0.f; hb1[i]=(_Float16)0.f; }
  if(eg0<E){
    hb0=*(const half8*)&h16g[(size_t)eg0*64 + gA*8];
    hb1=*(const half8*)&h16g[(size_t)eg0*64 + 32 + gA*8];
  }

  const half8* w2p=(const half8*)w2h;

  if(g==0){
    float p0[4]={};
    b1_step<0>(w3j,sh,shw[0],t,e0,E); __syncthreads();
    b2_step<0>(x,eidx,shw[0],ybuf[0],t,e0,E); b1_step<4>(w3j,sh,shw[1],t,e0,E); __syncthreads();
    comp_step<0,1>(ybuf[0],w2p,hb0,hb1,ln,eA,upb,wv,p0);
    b2_step<4>(x,eidx,shw[1],ybuf[1],t,e0,E); b1_step<9>(w3j,sh,shw[0],t,e0,E); __syncthreads();
    comp_step<4,1>(ybuf[1],w2p,hb0,hb1,ln,eA,upb,wv,p0);
    b2_step<9>(x,eidx,shw[0],ybuf[0],t,e0,E); __syncthreads();
    comp_step<9,1>(ybuf[0],w2p,hb0,hb1,ln,eA,upb,wv,p0);
    flush_set<1>(out,msgbuf,eg0,d0,E,0,pwc0,gA,wsel,wv,p0);
  } else if(g==1){
    float p0[12]={};
    b1_step<1>(w3j,sh,shw[0],t,e0,E); __syncthreads();
    b2_step<1>(x,eidx,shw[0],ybuf[0],t,e0,E); b1_step<3>(w3j,sh,shw[1],t,e0,E); __syncthreads();
    comp_step<1,3>(ybuf[0],w2p,hb0,hb1,ln,eA,upb,wv,p0);
    b2_step<3>(x,eidx,shw[1],ybuf[1],t,e0,E); b1_step<6>(w3j,sh,shw[0],t,e0,E); __syncthreads();
    comp_step<3,3>(ybuf[1],w2p,hb0,hb1,ln,eA,upb,wv,p0);
    b2_step<6>(x,eidx,shw[0],ybuf[0],t,e0,E); b1_step<8>(w3j,sh,shw[1],t,e0,E); __syncthreads();
    comp_step<6,3>(ybuf[0],w2p,hb0,hb1,ln,eA,upb,wv,p0);
    b2_step<8>(x,eidx,shw[1],ybuf[1],t,e0,E); __syncthreads();
    comp_step<8,3>(ybuf[1],w2p,hb0,hb1,ln,eA,upb,wv,p0);
    flush_set<3>(out,msgbuf,eg0,d0,E,32,pwc1,gA,wsel,wv,p0);
  } else {
    float p0[20]={};
    b1_step<2>(w3j,sh,shw[0],t,e0,E); __syncthreads();
    b2_step<2>(x,eidx,shw[0],ybuf[0],t,e0,E); b1_step<5>(w3j,sh,shw[1],t,e0,E); __syncthreads();
    comp_step<2,5>(ybuf[0],w2p,hb0,hb1,ln,eA,upb,wv,p0);
    b2_step<5>(x,eidx,shw[1],ybuf[1],t,e0,E); b1_step<7>(w3j,sh,shw[0],t,e0,E); __syncthreads();
    comp_step<5,5>(ybuf[1],w2p,hb0,hb1,ln,eA,upb,wv,p0);
    b2_step<7>(x,eidx,shw[0],ybuf[0],t,e0,E); b1_step<10>(w3j,sh,shw[1],t,e0,E); __syncthreads();
    comp_step<7,5>(ybuf[0],w2p,hb0,hb1,ln,eA,upb,wv,p0);
    b2_step<10>(x,eidx,shw[1],ybuf[1],t,e0,E); __syncthreads();
    comp_step<10,5>(ybuf[1],w2p,hb0,hb1,ln,eA,upb,wv,p0);
    flush_set<5>(out,msgbuf,eg0,d0,E,128,pwc2,gA,wsel,wv,p0);
  }
}

extern "C" void kernel_launch(void* const* d_in, const int* in_sizes, int n_in,
                              void* d_out, int out_size, void* d_ws, size_t ws_size,
                              hipStream_t stream){
  const float* x     =(const float*)d_in[0];
  const int*   eidx  =(const int*)  d_in[1];
  const float* sh    =(const float*)d_in[2];
  const float* radial=(const float*)d_in[3];
  const float* W1    =(const float*)d_in[4];
  const float* W2    =(const float*)d_in[5];
  const float* Wsc0  =(const float*)d_in[6];
  const float* Wsc1  =(const float*)d_in[7];
  const float* Wsc2  =(const float*)d_in[8];
  float* out=(float*)d_out;
  int n_nodes=in_sizes[0]/IND;
  int E=in_sizes[1]/2;

  float inv10=1.0f/sqrtf(10.0f);
  float pwc0=sqrtf(1.0f/96.0f) *0.125f*inv10;
  float pwc1=sqrtf(3.0f/128.0f)*0.125f*inv10;
  float pwc2=sqrtf(5.0f/128.0f)*0.125f*inv10;
  float silu_cst=1.67682f;

  // workspace layout
  size_t off=0;
  auto alloc=[&](size_t bytes)->size_t{ size_t o=off; off=(off+bytes+255)&~(size_t)255; return o; };
  size_t o_w3j = alloc(2048);
  size_t o_w2h = alloc((size_t)704*2*64*8*2);          // 1.44 MB f16
  size_t o_h16 = alloc((size_t)E*64*2);                // 2.56 MB f16
  size_t o_row = alloc((size_t)(n_nodes+64)*4);
  size_t o_cur = alloc((size_t)(n_nodes+64)*4);
  size_t o_eli = alloc((size_t)E*4);
  size_t o_msg = alloc((size_t)E*IND*4);               // 23 MB
  bool use_msg = (off <= ws_size) && (n_nodes <= 2048);

  char* ws=(char*)d_ws;
  float*     w3j =(float*)(ws+o_w3j);
  _Float16*  w2h =(_Float16*)(ws+o_w2h);
  _Float16*  h16g=(_Float16*)(ws+o_h16);
  int*       row =(int*)(ws+o_row);
  int*       cur =(int*)(ws+o_cur);
  int*       eli =(int*)(ws+o_eli);
  float*     msg =(float*)(ws+o_msg);

  int ntile=(E+TILE_E-1)/TILE_E;
  int hblocks=(E*64+255)/256;
  int prep_blocks = NINS+44+hblocks + (use_msg?1:0);

  hipLaunchKernelGGL(prep_kernel, dim3(prep_blocks), dim3(256), 0, stream,
                     w3j, W2, w2h, radial, W1, h16g, E, silu_cst,
                     eidx, row, cur, n_nodes, use_msg?1:0);

  if(use_msg){
    hipLaunchKernelGGL(fill_kernel, dim3((E+255)/256), dim3(256), 0, stream, eidx, cur, eli, E);
    hipLaunchKernelGGL(tp_kernel, dim3(3*ntile), dim3(256), 0, stream,
                       x, eidx, sh, h16g, w2h, w3j, out, msg, E, pwc0, pwc1, pwc2);
    hipLaunchKernelGGL(gather_kernel, dim3(n_nodes), dim3(256), 0, stream,
                       msg, row, eli, x, Wsc0, Wsc1, Wsc2, out, n_nodes);
  } else {
    hipLaunchKernelGGL(sc_kernel, dim3(n_nodes), dim3(256), 0, stream,
                       x, Wsc0, Wsc1, Wsc2, out, n_nodes);
    hipLaunchKernelGGL(tp_kernel, dim3(3*ntile), dim3(256), 0, stream,
                       x, eidx, sh, h16g, w2h, w3j, out, (float*)nullptr, E, pwc0, pwc1, pwc2);
  }
}